// Round 11
// baseline (475.056 us; speedup 1.0000x reference)
//
#include <hip/hip_runtime.h>
#include <hip/hip_fp16.h>

#define NN 262144   // nodes
#define NE 1048576  // edges
#define NG 8192     // graphs
#define FD 64       // feature dim
#define AD 8        // adduct dim
#define DN 512      // dense dim

// ---------------- CSR build ----------------
__global__ void k_count(const int* __restrict__ dst, int* __restrict__ counts,
                        int* __restrict__ rank) {
  int e = blockIdx.x * 256 + threadIdx.x;
  rank[e] = atomicAdd(&counts[dst[e]], 1);
}

__global__ void k_scan1(const int* __restrict__ counts, int* __restrict__ rp,
                        int* __restrict__ bsum) {
  __shared__ int s[256];
  int tid = threadIdx.x;
  int i = blockIdx.x * 256 + tid;
  int orig = counts[i];
  s[tid] = orig;
  __syncthreads();
  for (int off = 1; off < 256; off <<= 1) {
    int v = (tid >= off) ? s[tid - off] : 0;
    __syncthreads();
    s[tid] += v;
    __syncthreads();
  }
  rp[i] = s[tid] - orig;  // block-local exclusive scan
  if (tid == 255) bsum[blockIdx.x] = s[tid];
}

__global__ void k_scan2(int* __restrict__ bsum) {
  __shared__ int s[1024];
  int tid = threadIdx.x;
  int orig = bsum[tid];
  s[tid] = orig;
  __syncthreads();
  for (int off = 1; off < 1024; off <<= 1) {
    int v = (tid >= off) ? s[tid - off] : 0;
    __syncthreads();
    s[tid] += v;
    __syncthreads();
  }
  bsum[tid] = s[tid] - orig;  // exclusive
}

__global__ void k_scan3(const int* __restrict__ counts, int* __restrict__ rp,
                        const int* __restrict__ bsum, float* __restrict__ rsq) {
  int i = blockIdx.x * 256 + threadIdx.x;
  rp[i] = rp[i] + bsum[blockIdx.x];
  rsq[i] = rsqrtf((float)(counts[i] + 1));
  if (i == 0) rp[NN] = NE;
}

// Atomic-free XCD-partitioned scatter (validated R14). Plain src payload.
#define FILL_EPT 16
#define FILL_CHUNK (256 * FILL_EPT)
__global__ void k_fill(const int* __restrict__ src, const int* __restrict__ dst,
                       const int* __restrict__ rank, const int* __restrict__ rp,
                       int* __restrict__ csr_s) {
  int xcd = blockIdx.x & 7;
  int chunk = blockIdx.x >> 3;
  int base = chunk * FILL_CHUNK + threadIdx.x;
#pragma unroll
  for (int i = 0; i < FILL_EPT; i++) {
    int e = base + i * 256;
    int d = dst[e];
    if ((d >> 15) == xcd) {
      csr_s[rp[d] + rank[e]] = src[e];
    }
  }
}

// ---------------- fp16 row helpers (R19, validated) ----------------
__device__ __forceinline__ float4 ldrow_h(const uint2* __restrict__ th2,
                                          size_t n, int ln) {
  uint2 u = th2[n * 16 + ln];
  __half2 p0 = *reinterpret_cast<__half2*>(&u.x);
  __half2 p1 = *reinterpret_cast<__half2*>(&u.y);
  float2 f0 = __half22float2(p0);
  float2 f1 = __half22float2(p1);
  return make_float4(f0.x, f0.y, f1.x, f1.y);
}

__device__ __forceinline__ void strow_h(uint2* __restrict__ th2, size_t idx,
                                        float x, float y, float z, float w) {
  __half2 p0 = __floats2half2_rn(x, y);
  __half2 p1 = __floats2half2_rn(z, w);
  uint2 u;
  u.x = *reinterpret_cast<unsigned int*>(&p0);
  u.y = *reinterpret_cast<unsigned int*>(&p1);
  th2[idx] = u;
}

// ---------------- GCN layer 1: t' = (x @ W + b) * rsq[n]  (fp16 out) ------
#define HS 68  // row stride (floats): 272 B, 16B-aligned, breaks pow2 banks
__global__ void __launch_bounds__(256) k_transform(const float* __restrict__ hin,
                                                   const float* __restrict__ W,
                                                   const float* __restrict__ b,
                                                   const float* __restrict__ rsq,
                                                   uint2* __restrict__ tout) {
  __shared__ float hsT[64 * HS];  // [k][n]  17.4 KB
  int tid = threadIdx.x;
  size_t base = (size_t)blockIdx.x * 64 * 64;

  const float4* h4 = (const float4*)(hin + base);
#pragma unroll
  for (int j = 0; j < 4; j++) {
    int f = tid + 256 * j;
    int n = f >> 4, kq = f & 15;
    float4 v = h4[f];
    hsT[(4 * kq + 0) * HS + n] = v.x;
    hsT[(4 * kq + 1) * HS + n] = v.y;
    hsT[(4 * kq + 2) * HS + n] = v.z;
    hsT[(4 * kq + 3) * HS + n] = v.w;
  }
  __syncthreads();

  int n0 = (tid >> 4) * 4;
  int c0 = (tid & 15) * 4;
  float acc[4][4];
#pragma unroll
  for (int i = 0; i < 4; i++)
#pragma unroll
    for (int j = 0; j < 4; j++) acc[i][j] = b[c0 + j];

#pragma unroll 4
  for (int k = 0; k < 64; k++) {
    float4 av = *(const float4*)&hsT[k * HS + n0];   // ds_read_b128
    float4 bv = *(const float4*)&W[k * 64 + c0];     // global, L1-hit broadcast
    acc[0][0] = fmaf(av.x, bv.x, acc[0][0]);
    acc[0][1] = fmaf(av.x, bv.y, acc[0][1]);
    acc[0][2] = fmaf(av.x, bv.z, acc[0][2]);
    acc[0][3] = fmaf(av.x, bv.w, acc[0][3]);
    acc[1][0] = fmaf(av.y, bv.x, acc[1][0]);
    acc[1][1] = fmaf(av.y, bv.y, acc[1][1]);
    acc[1][2] = fmaf(av.y, bv.z, acc[1][2]);
    acc[1][3] = fmaf(av.y, bv.w, acc[1][3]);
    acc[2][0] = fmaf(av.z, bv.x, acc[2][0]);
    acc[2][1] = fmaf(av.z, bv.y, acc[2][1]);
    acc[2][2] = fmaf(av.z, bv.z, acc[2][2]);
    acc[2][3] = fmaf(av.z, bv.w, acc[2][3]);
    acc[3][0] = fmaf(av.w, bv.x, acc[3][0]);
    acc[3][1] = fmaf(av.w, bv.y, acc[3][1]);
    acc[3][2] = fmaf(av.w, bv.z, acc[3][2]);
    acc[3][3] = fmaf(av.w, bv.w, acc[3][3]);
  }

  int nbase = blockIdx.x * 64;
#pragma unroll
  for (int i = 0; i < 4; i++) {
    float rs = rsq[nbase + n0 + i];
    strow_h(tout, (size_t)(nbase + n0 + i) * 16 + (c0 >> 2),
            acc[i][0] * rs, acc[i][1] * rs, acc[i][2] * rs, acc[i][3] * rs);
  }
}

// ---------------- aggregation core (R16 engine, fp16 gather) ----------------
__device__ __forceinline__ void aggregate_nodes(const uint2* __restrict__ th2,
                                                const int* __restrict__ rp,
                                                const int* __restrict__ csr_s,
                                                const float* __restrict__ rsq,
                                                float* __restrict__ hacc,
                                                int nbase, int grp, int ln) {
  for (int r = 0; r < 4; r++) {
    int n = nbase + r * 16 + grp;
    int beg = rp[n], end = rp[n + 1];
    float rn = rsq[n];
    float4 a0 = ldrow_h(th2, (size_t)n, ln);  // self term t'[n]
    float4 a1 = make_float4(0.f, 0.f, 0.f, 0.f);
    float4 a2 = make_float4(0.f, 0.f, 0.f, 0.f);
    float4 a3 = make_float4(0.f, 0.f, 0.f, 0.f);

    int idx = beg;
    for (; idx + 4 <= end; idx += 4) {
      int s0 = csr_s[idx + 0];
      int s1 = csr_s[idx + 1];
      int s2 = csr_s[idx + 2];
      int s3 = csr_s[idx + 3];
      float4 v0 = ldrow_h(th2, (size_t)s0, ln);
      float4 v1 = ldrow_h(th2, (size_t)s1, ln);
      float4 v2 = ldrow_h(th2, (size_t)s2, ln);
      float4 v3 = ldrow_h(th2, (size_t)s3, ln);
      a0.x += v0.x; a0.y += v0.y; a0.z += v0.z; a0.w += v0.w;
      a1.x += v1.x; a1.y += v1.y; a1.z += v1.z; a1.w += v1.w;
      a2.x += v2.x; a2.y += v2.y; a2.z += v2.z; a2.w += v2.w;
      a3.x += v3.x; a3.y += v3.y; a3.z += v3.z; a3.w += v3.w;
    }
    if (idx + 2 <= end) {
      int s0 = csr_s[idx + 0];
      int s1 = csr_s[idx + 1];
      float4 v0 = ldrow_h(th2, (size_t)s0, ln);
      float4 v1 = ldrow_h(th2, (size_t)s1, ln);
      a0.x += v0.x; a0.y += v0.y; a0.z += v0.z; a0.w += v0.w;
      a1.x += v1.x; a1.y += v1.y; a1.z += v1.z; a1.w += v1.w;
      idx += 2;
    }
    if (idx < end) {
      int s0 = csr_s[idx];
      float4 v0 = ldrow_h(th2, (size_t)s0, ln);
      a0.x += v0.x; a0.y += v0.y; a0.z += v0.z; a0.w += v0.w;
    }
    int nl = r * 16 + grp;
    float4 v;
    v.x = fmaxf(rn * ((a0.x + a1.x) + (a2.x + a3.x)), 0.f);
    v.y = fmaxf(rn * ((a0.y + a1.y) + (a2.y + a3.y)), 0.f);
    v.z = fmaxf(rn * ((a0.z + a1.z) + (a2.z + a3.z)), 0.f);
    v.w = fmaxf(rn * ((a0.w + a1.w) + (a2.w + a3.w)), 0.f);
    *(float4*)&hacc[nl * HS + 4 * ln] = v;  // 2-way wrap -> conflict-free
  }
}

// Fused aggregate + next-layer transform (h never touches HBM).
__global__ void __launch_bounds__(256) k_aggT(const uint2* __restrict__ tin,
                                              const int* __restrict__ rp,
                                              const int* __restrict__ csr_s,
                                              const float* __restrict__ rsq,
                                              const float* __restrict__ W,
                                              const float* __restrict__ b,
                                              uint2* __restrict__ tout) {
  __shared__ float hacc[64 * HS];  // [n][k] h' tile, 17.4 KB
  int tid = threadIdx.x;
  int grp = tid >> 4;
  int ln = tid & 15;
  int nbase = blockIdx.x * 64;

  aggregate_nodes(tin, rp, csr_s, rsq, hacc, nbase, grp, ln);
  __syncthreads();

  // GEMM: tout[n][c] = (h'[n][:] @ W + b) * rsq[n]
  int n0 = (tid >> 4) * 4;
  int c0 = (tid & 15) * 4;
  float acc[4][4];
#pragma unroll
  for (int i = 0; i < 4; i++)
#pragma unroll
    for (int j = 0; j < 4; j++) acc[i][j] = b[c0 + j];

#pragma unroll 4
  for (int k = 0; k < 64; k++) {
    float a0 = hacc[(n0 + 0) * HS + k];  // same-addr broadcast per quarter-wave
    float a1 = hacc[(n0 + 1) * HS + k];
    float a2 = hacc[(n0 + 2) * HS + k];
    float a3 = hacc[(n0 + 3) * HS + k];
    float4 bv = *(const float4*)&W[k * 64 + c0];  // global, L1-hit
    acc[0][0] = fmaf(a0, bv.x, acc[0][0]);
    acc[0][1] = fmaf(a0, bv.y, acc[0][1]);
    acc[0][2] = fmaf(a0, bv.z, acc[0][2]);
    acc[0][3] = fmaf(a0, bv.w, acc[0][3]);
    acc[1][0] = fmaf(a1, bv.x, acc[1][0]);
    acc[1][1] = fmaf(a1, bv.y, acc[1][1]);
    acc[1][2] = fmaf(a1, bv.z, acc[1][2]);
    acc[1][3] = fmaf(a1, bv.w, acc[1][3]);
    acc[2][0] = fmaf(a2, bv.x, acc[2][0]);
    acc[2][1] = fmaf(a2, bv.y, acc[2][1]);
    acc[2][2] = fmaf(a2, bv.z, acc[2][2]);
    acc[2][3] = fmaf(a2, bv.w, acc[2][3]);
    acc[3][0] = fmaf(a3, bv.x, acc[3][0]);
    acc[3][1] = fmaf(a3, bv.y, acc[3][1]);
    acc[3][2] = fmaf(a3, bv.z, acc[3][2]);
    acc[3][3] = fmaf(a3, bv.w, acc[3][3]);
  }

#pragma unroll
  for (int i = 0; i < 4; i++) {
    float rs = rsq[nbase + n0 + i];
    strow_h(tout, (size_t)(nbase + n0 + i) * 16 + (c0 >> 2),
            acc[i][0] * rs, acc[i][1] * rs, acc[i][2] * rs, acc[i][3] * rs);
  }
}

// ---------------- R18: fused final aggregate + readout ----------------
__global__ void __launch_bounds__(256) k_aggR(const uint2* __restrict__ tin,
                                              const int* __restrict__ rp,
                                              const int* __restrict__ csr_s,
                                              const float* __restrict__ rsq,
                                              const int* __restrict__ gids,
                                              float* __restrict__ r) {
  __shared__ float hacc[64 * HS];
  __shared__ int gl[64];
  int tid = threadIdx.x;
  int grp = tid >> 4;
  int ln = tid & 15;
  int nbase = blockIdx.x * 64;
  if (tid < 64) gl[tid] = gids[nbase + tid];

  aggregate_nodes(tin, rp, csr_s, rsq, hacc, nbase, grp, ln);
  __syncthreads();

  // Segmented reduce: wave w handles rows [w*16, w*16+16), lane = column.
  int c = tid & 63;
  int row0 = (tid >> 6) * 16;
  int cur = gl[row0];
  float run = 0.f;
  for (int rr = 0; rr < 16; rr++) {
    int g = gl[row0 + rr];
    float v = hacc[(row0 + rr) * HS + c];
    if (g != cur) {
      atomicAdd(&r[(size_t)cur * 64 + c], run);
      cur = g;
      run = v;
    } else {
      run += v;
    }
  }
  atomicAdd(&r[(size_t)cur * 64 + c], run);
}

// ---------------- Dense head ----------------
// R23: y1T stored fp16 (rounding validated safe for t in R19). Halves y1T
// HBM traffic and enables dense2's 1-ds_read-per-8-g layout.
__global__ void __launch_bounds__(256) k_dense1(const float* __restrict__ r,
                                                const float* __restrict__ xa,
                                                const float* __restrict__ W1,
                                                const float* __restrict__ b1,
                                                const float* __restrict__ ob,
                                                float* __restrict__ out,
                                                __half* __restrict__ y1h) {
  __shared__ float xs[8 * 72];
  int tid = threadIdx.x;
  int g0 = blockIdx.x * 8;
  if (tid < 8) out[g0 + tid] = ob[0];
  for (int i = tid; i < 8 * 72; i += 256) {
    int g = i / 72, k = i % 72;
    xs[i] = (k < 64) ? r[(size_t)(g0 + g) * 64 + k] : xa[(size_t)(g0 + g) * 8 + (k - 64)];
  }
  __syncthreads();
  float acc[8][2];
#pragma unroll
  for (int g = 0; g < 8; g++) { acc[g][0] = 0.f; acc[g][1] = 0.f; }
  for (int k = 0; k < 72; k++) {
    float w0 = W1[k * 512 + tid];
    float w1 = W1[k * 512 + 256 + tid];
#pragma unroll
    for (int g = 0; g < 8; g++) {
      float xv = xs[g * 72 + k];
      acc[g][0] = fmaf(xv, w0, acc[g][0]);
      acc[g][1] = fmaf(xv, w1, acc[g][1]);
    }
  }
  float bb0 = b1[tid], bb1 = b1[256 + tid];
  strow_h((uint2*)y1h, ((size_t)tid * NG + g0) >> 2,
          fmaxf(acc[0][0] + bb0, 0.f), fmaxf(acc[1][0] + bb0, 0.f),
          fmaxf(acc[2][0] + bb0, 0.f), fmaxf(acc[3][0] + bb0, 0.f));
  strow_h((uint2*)y1h, ((size_t)tid * NG + g0 + 4) >> 2,
          fmaxf(acc[4][0] + bb0, 0.f), fmaxf(acc[5][0] + bb0, 0.f),
          fmaxf(acc[6][0] + bb0, 0.f), fmaxf(acc[7][0] + bb0, 0.f));
  strow_h((uint2*)y1h, ((size_t)(256 + tid) * NG + g0) >> 2,
          fmaxf(acc[0][1] + bb1, 0.f), fmaxf(acc[1][1] + bb1, 0.f),
          fmaxf(acc[2][1] + bb1, 0.f), fmaxf(acc[3][1] + bb1, 0.f));
  strow_h((uint2*)y1h, ((size_t)(256 + tid) * NG + g0 + 4) >> 2,
          fmaxf(acc[4][1] + bb1, 0.f), fmaxf(acc[5][1] + bb1, 0.f),
          fmaxf(acc[6][1] + bb1, 0.f), fmaxf(acc[7][1] + bb1, 0.f));
}

// R23: dense2 engine. R19-R22 established: LDS instruction stream is the
// bound (3 b128/thread-k = 62 us floor; 77.8 measured at 2 blocks/CU).
// fp16 x-tile + 8-CONTIGUOUS-g per thread: x read = 1 ds_read_b128 (8
// halves; lanes 0-15 span 256B = 2-way wrap free, others broadcast), W
// fp32 = 1 b128. 2 insts/32 FMA -> LDS floor ~41 us; VALU +8 cvt/k ->
// ~34 us. W2 NOT rounded (fp32 LDS).
#define DBK 32
__global__ void __launch_bounds__(256) k_dense2(const __half* __restrict__ y1h,
                                                const float* __restrict__ W2,
                                                const float* __restrict__ b2,
                                                const float* __restrict__ ow,
                                                float* __restrict__ out) {
  __shared__ __half xs[DBK * 128];  // [k][g] fp16, 8 KB
  __shared__ float ws[DBK * 64];    // [k][j] fp32, 8 KB
  __shared__ float po[128];
  int tid = threadIdx.x;  // 256
  int g0 = (blockIdx.x & 63) * 128;
  int j0 = (blockIdx.x >> 6) * 64;
  int ga8 = (tid & 15) * 8;  // 8 contiguous g per thread
  int jb = (tid >> 4) * 4;   // j quad

  float acc[4][8];  // [j][g]
#pragma unroll
  for (int jl = 0; jl < 4; jl++) {
    float bb = b2[j0 + jb + jl];
#pragma unroll
    for (int gg = 0; gg < 8; gg++) acc[jl][gg] = bb;
  }

  for (int kb = 0; kb < 512; kb += DBK) {
    __syncthreads();
    // stage x-tile [32k][128g] halves: 512 uint4 (8 halves each), 2/thread
#pragma unroll
    for (int i = 0; i < 2; i++) {
      int f = tid + 256 * i;
      int kr = f >> 4, gc = f & 15;  // 16 uint4 per 128-half row
      ((uint4*)xs)[f] =
          ((const uint4*)(y1h + (size_t)(kb + kr) * NG + g0))[gc];
    }
    // stage W-tile [32k][64j] fp32: 512 float4, 2/thread
#pragma unroll
    for (int i = 0; i < 2; i++) {
      int f = tid + 256 * i;
      int kr = f >> 4, jc = f & 15;
      ((float4*)ws)[f] = ((const float4*)(W2 + (size_t)(kb + kr) * 512 + j0))[jc];
    }
    __syncthreads();
#pragma unroll 4
    for (int k = 0; k < DBK; k++) {
      uint4 xu = *(const uint4*)&xs[k * 128 + ga8];   // ds_read_b128: 8 halves
      float4 w0 = *(const float4*)&ws[k * 64 + jb];   // ds_read_b128: 4 floats
      float2 f0 = __half22float2(*reinterpret_cast<__half2*>(&xu.x));
      float2 f1 = __half22float2(*reinterpret_cast<__half2*>(&xu.y));
      float2 f2 = __half22float2(*reinterpret_cast<__half2*>(&xu.z));
      float2 f3 = __half22float2(*reinterpret_cast<__half2*>(&xu.w));
      float xv[8] = {f0.x, f0.y, f1.x, f1.y, f2.x, f2.y, f3.x, f3.y};
      float wv[4] = {w0.x, w0.y, w0.z, w0.w};
#pragma unroll
      for (int jj = 0; jj < 4; jj++)
#pragma unroll
        for (int gg = 0; gg < 8; gg++)
          acc[jj][gg] = fmaf(wv[jj], xv[gg], acc[jj][gg]);
    }
  }

  // fused out-epilogue (R18 scheme, g-mapping = ga8+gg)
  if (tid < 128) po[tid] = 0.f;
  __syncthreads();
  float4 owv = *(const float4*)&ow[j0 + jb];
#pragma unroll
  for (int gg = 0; gg < 8; gg++) {
    float pv = fmaxf(acc[0][gg], 0.f) * owv.x + fmaxf(acc[1][gg], 0.f) * owv.y +
               fmaxf(acc[2][gg], 0.f) * owv.z + fmaxf(acc[3][gg], 0.f) * owv.w;
    // lanes l, l^16, l^32, l^48 share tid&15 -> same ga8
    pv += __shfl_xor(pv, 16);
    pv += __shfl_xor(pv, 32);
    if ((tid & 48) == 0) atomicAdd(&po[ga8 + gg], pv);
  }
  __syncthreads();
  if (tid < 128) atomicAdd(&out[g0 + tid], po[tid]);
}

extern "C" void kernel_launch(void* const* d_in, const int* in_sizes, int n_in,
                              void* d_out, int out_size, void* d_ws, size_t ws_size,
                              hipStream_t stream) {
  const float* x_mol    = (const float*)d_in[0];
  const float* x_adduct = (const float*)d_in[1];
  const int*   edge_src = (const int*)d_in[2];
  const int*   edge_dst = (const int*)d_in[3];
  const int*   graph_ids= (const int*)d_in[4];
  const float* gcn_W    = (const float*)d_in[5];
  const float* gcn_b    = (const float*)d_in[6];
  const float* d1W      = (const float*)d_in[7];
  const float* d1b      = (const float*)d_in[8];
  const float* d2W      = (const float*)d_in[9];
  const float* d2b      = (const float*)d_in[10];
  const float* oW       = (const float*)d_in[11];
  const float* obias    = (const float*)d_in[12];
  float* out = (float*)d_out;

  char* p = (char*)d_ws;
  auto alloc = [&](size_t bytes) {
    char* q = p;
    p += (bytes + 255) & ~(size_t)255;
    return q;
  };
  int*    counts = (int*)alloc((size_t)NN * 4);
  int*    rp     = (int*)alloc((size_t)(NN + 1) * 4);
  int*    bsum   = (int*)alloc(1024 * 4);
  float*  rsq    = (float*)alloc((size_t)NN * 4);
  int*    rank   = (int*)alloc((size_t)NE * 4);
  int*    csr_s  = (int*)alloc((size_t)NE * 4);
  uint2*  th_a   = (uint2*)alloc((size_t)NN * 64 * 2);  // fp16 t rows (32 MB)
  uint2*  th_b   = (uint2*)alloc((size_t)NN * 64 * 2);
  float*  r      = (float*)alloc((size_t)NG * 64 * 4);
  __half* y1h    = (__half*)alloc((size_t)NG * 512 * 2);  // fp16 y1T (8 MB)

  hipMemsetAsync(counts, 0, (size_t)NN * 4, stream);
  hipMemsetAsync(r, 0, (size_t)NG * 64 * 4, stream);
  k_count<<<NE / 256, 256, 0, stream>>>(edge_dst, counts, rank);
  k_scan1<<<NN / 256, 256, 0, stream>>>(counts, rp, bsum);
  k_scan2<<<1, 1024, 0, stream>>>(bsum);
  k_scan3<<<NN / 256, 256, 0, stream>>>(counts, rp, bsum, rsq);
  k_fill<<<8 * (NE / FILL_CHUNK), 256, 0, stream>>>(edge_src, edge_dst, rank, rp, csr_s);

  // t1 = transform(x_mol); t2 = aggT(t1); t3 = aggT(t2); r = aggR(t3)
  k_transform<<<NN / 64, 256, 0, stream>>>(x_mol, gcn_W, gcn_b, rsq, th_a);
  k_aggT<<<NN / 64, 256, 0, stream>>>(th_a, rp, csr_s, rsq,
                                      gcn_W + (size_t)1 * 64 * 64,
                                      gcn_b + (size_t)1 * 64, th_b);
  k_aggT<<<NN / 64, 256, 0, stream>>>(th_b, rp, csr_s, rsq,
                                      gcn_W + (size_t)2 * 64 * 64,
                                      gcn_b + (size_t)2 * 64, th_a);
  k_aggR<<<NN / 64, 256, 0, stream>>>(th_a, rp, csr_s, rsq, graph_ids, r);

  k_dense1<<<NG / 8, 256, 0, stream>>>(r, x_adduct, d1W, d1b, obias, out, y1h);
  k_dense2<<<512, 256, 0, stream>>>(y1h, d2W, d2b, oW, out);
}

// Round 12
// 445.845 us; speedup vs baseline: 1.0655x; 1.0655x over previous
//
#include <hip/hip_runtime.h>
#include <hip/hip_fp16.h>

#define NN 262144   // nodes
#define NE 1048576  // edges
#define NG 8192     // graphs
#define FD 64       // feature dim
#define AD 8        // adduct dim
#define DN 512      // dense dim

// ---------------- CSR build ----------------
__global__ void k_count(const int* __restrict__ dst, int* __restrict__ counts,
                        int* __restrict__ rank) {
  int e = blockIdx.x * 256 + threadIdx.x;
  rank[e] = atomicAdd(&counts[dst[e]], 1);
}

__global__ void k_scan1(const int* __restrict__ counts, int* __restrict__ rp,
                        int* __restrict__ bsum) {
  __shared__ int s[256];
  int tid = threadIdx.x;
  int i = blockIdx.x * 256 + tid;
  int orig = counts[i];
  s[tid] = orig;
  __syncthreads();
  for (int off = 1; off < 256; off <<= 1) {
    int v = (tid >= off) ? s[tid - off] : 0;
    __syncthreads();
    s[tid] += v;
    __syncthreads();
  }
  rp[i] = s[tid] - orig;  // block-local exclusive scan
  if (tid == 255) bsum[blockIdx.x] = s[tid];
}

__global__ void k_scan2(int* __restrict__ bsum) {
  __shared__ int s[1024];
  int tid = threadIdx.x;
  int orig = bsum[tid];
  s[tid] = orig;
  __syncthreads();
  for (int off = 1; off < 1024; off <<= 1) {
    int v = (tid >= off) ? s[tid - off] : 0;
    __syncthreads();
    s[tid] += v;
    __syncthreads();
  }
  bsum[tid] = s[tid] - orig;  // exclusive
}

__global__ void k_scan3(const int* __restrict__ counts, int* __restrict__ rp,
                        const int* __restrict__ bsum, float* __restrict__ rsq) {
  int i = blockIdx.x * 256 + threadIdx.x;
  rp[i] = rp[i] + bsum[blockIdx.x];
  rsq[i] = rsqrtf((float)(counts[i] + 1));
  if (i == 0) rp[NN] = NE;
}

// Atomic-free XCD-partitioned scatter (validated R14). Plain src payload.
#define FILL_EPT 16
#define FILL_CHUNK (256 * FILL_EPT)
__global__ void k_fill(const int* __restrict__ src, const int* __restrict__ dst,
                       const int* __restrict__ rank, const int* __restrict__ rp,
                       int* __restrict__ csr_s) {
  int xcd = blockIdx.x & 7;
  int chunk = blockIdx.x >> 3;
  int base = chunk * FILL_CHUNK + threadIdx.x;
#pragma unroll
  for (int i = 0; i < FILL_EPT; i++) {
    int e = base + i * 256;
    int d = dst[e];
    if ((d >> 15) == xcd) {
      csr_s[rp[d] + rank[e]] = src[e];
    }
  }
}

// ---------------- fp16 helpers (R19/R23, validated) ----------------
__device__ __forceinline__ float4 ldrow_h(const uint2* __restrict__ th2,
                                          size_t n, int ln) {
  uint2 u = th2[n * 16 + ln];
  __half2 p0 = *reinterpret_cast<__half2*>(&u.x);
  __half2 p1 = *reinterpret_cast<__half2*>(&u.y);
  float2 f0 = __half22float2(p0);
  float2 f1 = __half22float2(p1);
  return make_float4(f0.x, f0.y, f1.x, f1.y);
}

__device__ __forceinline__ void strow_h(uint2* __restrict__ th2, size_t idx,
                                        float x, float y, float z, float w) {
  __half2 p0 = __floats2half2_rn(x, y);
  __half2 p1 = __floats2half2_rn(z, w);
  uint2 u;
  u.x = *reinterpret_cast<unsigned int*>(&p0);
  u.y = *reinterpret_cast<unsigned int*>(&p1);
  th2[idx] = u;
}

__device__ __forceinline__ unsigned int f2h2(float x, float y) {
  __half2 p = __floats2half2_rn(x, y);
  return *reinterpret_cast<unsigned int*>(&p);
}

// R24: fp16-pair dot product with fp32 accumulate. Products are exact
// (11-bit mantissas fit fp32); only input roundings matter.
#if __has_builtin(__builtin_amdgcn_fdot2)
typedef _Float16 half2v __attribute__((ext_vector_type(2)));
__device__ __forceinline__ float fdot2(unsigned int a, unsigned int b, float c) {
  half2v ah = __builtin_bit_cast(half2v, a);
  half2v bh = __builtin_bit_cast(half2v, b);
  return __builtin_amdgcn_fdot2(ah, bh, c, false);
}
#else
__device__ __forceinline__ float fdot2(unsigned int a, unsigned int b, float c) {
  float2 af = __half22float2(*reinterpret_cast<__half2*>(&a));
  float2 bf = __half22float2(*reinterpret_cast<__half2*>(&b));
  return fmaf(af.y, bf.y, fmaf(af.x, bf.x, c));
}
#endif

// ---------------- GCN layer 1: t' = (x @ W + b) * rsq[n]  (fp16 out) ------
#define HS 68  // row stride (floats): 272 B, 16B-aligned, breaks pow2 banks
__global__ void __launch_bounds__(256) k_transform(const float* __restrict__ hin,
                                                   const float* __restrict__ W,
                                                   const float* __restrict__ b,
                                                   const float* __restrict__ rsq,
                                                   uint2* __restrict__ tout) {
  __shared__ float hsT[64 * HS];  // [k][n]  17.4 KB
  int tid = threadIdx.x;
  size_t base = (size_t)blockIdx.x * 64 * 64;

  const float4* h4 = (const float4*)(hin + base);
#pragma unroll
  for (int j = 0; j < 4; j++) {
    int f = tid + 256 * j;
    int n = f >> 4, kq = f & 15;
    float4 v = h4[f];
    hsT[(4 * kq + 0) * HS + n] = v.x;
    hsT[(4 * kq + 1) * HS + n] = v.y;
    hsT[(4 * kq + 2) * HS + n] = v.z;
    hsT[(4 * kq + 3) * HS + n] = v.w;
  }
  __syncthreads();

  int n0 = (tid >> 4) * 4;
  int c0 = (tid & 15) * 4;
  float acc[4][4];
#pragma unroll
  for (int i = 0; i < 4; i++)
#pragma unroll
    for (int j = 0; j < 4; j++) acc[i][j] = b[c0 + j];

#pragma unroll 4
  for (int k = 0; k < 64; k++) {
    float4 av = *(const float4*)&hsT[k * HS + n0];   // ds_read_b128
    float4 bv = *(const float4*)&W[k * 64 + c0];     // global, L1-hit broadcast
    acc[0][0] = fmaf(av.x, bv.x, acc[0][0]);
    acc[0][1] = fmaf(av.x, bv.y, acc[0][1]);
    acc[0][2] = fmaf(av.x, bv.z, acc[0][2]);
    acc[0][3] = fmaf(av.x, bv.w, acc[0][3]);
    acc[1][0] = fmaf(av.y, bv.x, acc[1][0]);
    acc[1][1] = fmaf(av.y, bv.y, acc[1][1]);
    acc[1][2] = fmaf(av.y, bv.z, acc[1][2]);
    acc[1][3] = fmaf(av.y, bv.w, acc[1][3]);
    acc[2][0] = fmaf(av.z, bv.x, acc[2][0]);
    acc[2][1] = fmaf(av.z, bv.y, acc[2][1]);
    acc[2][2] = fmaf(av.z, bv.z, acc[2][2]);
    acc[2][3] = fmaf(av.z, bv.w, acc[2][3]);
    acc[3][0] = fmaf(av.w, bv.x, acc[3][0]);
    acc[3][1] = fmaf(av.w, bv.y, acc[3][1]);
    acc[3][2] = fmaf(av.w, bv.z, acc[3][2]);
    acc[3][3] = fmaf(av.w, bv.w, acc[3][3]);
  }

  int nbase = blockIdx.x * 64;
#pragma unroll
  for (int i = 0; i < 4; i++) {
    float rs = rsq[nbase + n0 + i];
    strow_h(tout, (size_t)(nbase + n0 + i) * 16 + (c0 >> 2),
            acc[i][0] * rs, acc[i][1] * rs, acc[i][2] * rs, acc[i][3] * rs);
  }
}

// ---------------- aggregation core (R16 engine, fp16 gather) ----------------
__device__ __forceinline__ void aggregate_nodes(const uint2* __restrict__ th2,
                                                const int* __restrict__ rp,
                                                const int* __restrict__ csr_s,
                                                const float* __restrict__ rsq,
                                                float* __restrict__ hacc,
                                                int nbase, int grp, int ln) {
  for (int r = 0; r < 4; r++) {
    int n = nbase + r * 16 + grp;
    int beg = rp[n], end = rp[n + 1];
    float rn = rsq[n];
    float4 a0 = ldrow_h(th2, (size_t)n, ln);  // self term t'[n]
    float4 a1 = make_float4(0.f, 0.f, 0.f, 0.f);
    float4 a2 = make_float4(0.f, 0.f, 0.f, 0.f);
    float4 a3 = make_float4(0.f, 0.f, 0.f, 0.f);

    int idx = beg;
    for (; idx + 4 <= end; idx += 4) {
      int s0 = csr_s[idx + 0];
      int s1 = csr_s[idx + 1];
      int s2 = csr_s[idx + 2];
      int s3 = csr_s[idx + 3];
      float4 v0 = ldrow_h(th2, (size_t)s0, ln);
      float4 v1 = ldrow_h(th2, (size_t)s1, ln);
      float4 v2 = ldrow_h(th2, (size_t)s2, ln);
      float4 v3 = ldrow_h(th2, (size_t)s3, ln);
      a0.x += v0.x; a0.y += v0.y; a0.z += v0.z; a0.w += v0.w;
      a1.x += v1.x; a1.y += v1.y; a1.z += v1.z; a1.w += v1.w;
      a2.x += v2.x; a2.y += v2.y; a2.z += v2.z; a2.w += v2.w;
      a3.x += v3.x; a3.y += v3.y; a3.z += v3.z; a3.w += v3.w;
    }
    if (idx + 2 <= end) {
      int s0 = csr_s[idx + 0];
      int s1 = csr_s[idx + 1];
      float4 v0 = ldrow_h(th2, (size_t)s0, ln);
      float4 v1 = ldrow_h(th2, (size_t)s1, ln);
      a0.x += v0.x; a0.y += v0.y; a0.z += v0.z; a0.w += v0.w;
      a1.x += v1.x; a1.y += v1.y; a1.z += v1.z; a1.w += v1.w;
      idx += 2;
    }
    if (idx < end) {
      int s0 = csr_s[idx];
      float4 v0 = ldrow_h(th2, (size_t)s0, ln);
      a0.x += v0.x; a0.y += v0.y; a0.z += v0.z; a0.w += v0.w;
    }
    int nl = r * 16 + grp;
    float4 v;
    v.x = fmaxf(rn * ((a0.x + a1.x) + (a2.x + a3.x)), 0.f);
    v.y = fmaxf(rn * ((a0.y + a1.y) + (a2.y + a3.y)), 0.f);
    v.z = fmaxf(rn * ((a0.z + a1.z) + (a2.z + a3.z)), 0.f);
    v.w = fmaxf(rn * ((a0.w + a1.w) + (a2.w + a3.w)), 0.f);
    *(float4*)&hacc[nl * HS + 4 * ln] = v;  // 2-way wrap -> conflict-free
  }
}

// Fused aggregate + next-layer transform (h never touches HBM).
__global__ void __launch_bounds__(256) k_aggT(const uint2* __restrict__ tin,
                                              const int* __restrict__ rp,
                                              const int* __restrict__ csr_s,
                                              const float* __restrict__ rsq,
                                              const float* __restrict__ W,
                                              const float* __restrict__ b,
                                              uint2* __restrict__ tout) {
  __shared__ float hacc[64 * HS];  // [n][k] h' tile, 17.4 KB
  int tid = threadIdx.x;
  int grp = tid >> 4;
  int ln = tid & 15;
  int nbase = blockIdx.x * 64;

  aggregate_nodes(tin, rp, csr_s, rsq, hacc, nbase, grp, ln);
  __syncthreads();

  // GEMM: tout[n][c] = (h'[n][:] @ W + b) * rsq[n]
  int n0 = (tid >> 4) * 4;
  int c0 = (tid & 15) * 4;
  float acc[4][4];
#pragma unroll
  for (int i = 0; i < 4; i++)
#pragma unroll
    for (int j = 0; j < 4; j++) acc[i][j] = b[c0 + j];

#pragma unroll 4
  for (int k = 0; k < 64; k++) {
    float a0 = hacc[(n0 + 0) * HS + k];  // same-addr broadcast per quarter-wave
    float a1 = hacc[(n0 + 1) * HS + k];
    float a2 = hacc[(n0 + 2) * HS + k];
    float a3 = hacc[(n0 + 3) * HS + k];
    float4 bv = *(const float4*)&W[k * 64 + c0];  // global, L1-hit
    acc[0][0] = fmaf(a0, bv.x, acc[0][0]);
    acc[0][1] = fmaf(a0, bv.y, acc[0][1]);
    acc[0][2] = fmaf(a0, bv.z, acc[0][2]);
    acc[0][3] = fmaf(a0, bv.w, acc[0][3]);
    acc[1][0] = fmaf(a1, bv.x, acc[1][0]);
    acc[1][1] = fmaf(a1, bv.y, acc[1][1]);
    acc[1][2] = fmaf(a1, bv.z, acc[1][2]);
    acc[1][3] = fmaf(a1, bv.w, acc[1][3]);
    acc[2][0] = fmaf(a2, bv.x, acc[2][0]);
    acc[2][1] = fmaf(a2, bv.y, acc[2][1]);
    acc[2][2] = fmaf(a2, bv.z, acc[2][2]);
    acc[2][3] = fmaf(a2, bv.w, acc[2][3]);
    acc[3][0] = fmaf(a3, bv.x, acc[3][0]);
    acc[3][1] = fmaf(a3, bv.y, acc[3][1]);
    acc[3][2] = fmaf(a3, bv.z, acc[3][2]);
    acc[3][3] = fmaf(a3, bv.w, acc[3][3]);
  }

#pragma unroll
  for (int i = 0; i < 4; i++) {
    float rs = rsq[nbase + n0 + i];
    strow_h(tout, (size_t)(nbase + n0 + i) * 16 + (c0 >> 2),
            acc[i][0] * rs, acc[i][1] * rs, acc[i][2] * rs, acc[i][3] * rs);
  }
}

// ---------------- R18: fused final aggregate + readout ----------------
__global__ void __launch_bounds__(256) k_aggR(const uint2* __restrict__ tin,
                                              const int* __restrict__ rp,
                                              const int* __restrict__ csr_s,
                                              const float* __restrict__ rsq,
                                              const int* __restrict__ gids,
                                              float* __restrict__ r) {
  __shared__ float hacc[64 * HS];
  __shared__ int gl[64];
  int tid = threadIdx.x;
  int grp = tid >> 4;
  int ln = tid & 15;
  int nbase = blockIdx.x * 64;
  if (tid < 64) gl[tid] = gids[nbase + tid];

  aggregate_nodes(tin, rp, csr_s, rsq, hacc, nbase, grp, ln);
  __syncthreads();

  // Segmented reduce: wave w handles rows [w*16, w*16+16), lane = column.
  int c = tid & 63;
  int row0 = (tid >> 6) * 16;
  int cur = gl[row0];
  float run = 0.f;
  for (int rr = 0; rr < 16; rr++) {
    int g = gl[row0 + rr];
    float v = hacc[(row0 + rr) * HS + c];
    if (g != cur) {
      atomicAdd(&r[(size_t)cur * 64 + c], run);
      cur = g;
      run = v;
    } else {
      run += v;
    }
  }
  atomicAdd(&r[(size_t)cur * 64 + c], run);
}

// ---------------- R24: pack W2 into k-paired half2 ----------------
__global__ void k_packW(const float* __restrict__ W2, unsigned int* __restrict__ W2h) {
  int idx = blockIdx.x * 256 + threadIdx.x;  // 256 k2 x 512 j
  int k2 = idx >> 9, j = idx & 511;
  W2h[idx] = f2h2(W2[(size_t)(2 * k2) * 512 + j], W2[(size_t)(2 * k2 + 1) * 512 + j]);
}

// ---------------- Dense head ----------------
// R24: dense1 handles the ADJACENT j-pair (2tid, 2tid+1) and emits y1 as
// k-paired half2 (y1p[j2][g] = {y1[2j2][g], y1[2j2+1][g]}), so dense2's
// dot2 operands need no repacking. fp16 y1 rounding: R23 measured zero
// absmax delta.
__global__ void __launch_bounds__(256) k_dense1(const float* __restrict__ r,
                                                const float* __restrict__ xa,
                                                const float* __restrict__ W1,
                                                const float* __restrict__ b1,
                                                const float* __restrict__ ob,
                                                float* __restrict__ out,
                                                unsigned int* __restrict__ y1p) {
  __shared__ float xs[8 * 72];
  int tid = threadIdx.x;
  int g0 = blockIdx.x * 8;
  if (tid < 8) out[g0 + tid] = ob[0];
  for (int i = tid; i < 8 * 72; i += 256) {
    int g = i / 72, k = i % 72;
    xs[i] = (k < 64) ? r[(size_t)(g0 + g) * 64 + k] : xa[(size_t)(g0 + g) * 8 + (k - 64)];
  }
  __syncthreads();
  float acc[8][2];
#pragma unroll
  for (int g = 0; g < 8; g++) { acc[g][0] = 0.f; acc[g][1] = 0.f; }
  for (int k = 0; k < 72; k++) {
    float2 wp = *(const float2*)&W1[k * 512 + 2 * tid];  // adjacent j-pair
#pragma unroll
    for (int g = 0; g < 8; g++) {
      float xv = xs[g * 72 + k];
      acc[g][0] = fmaf(xv, wp.x, acc[g][0]);
      acc[g][1] = fmaf(xv, wp.y, acc[g][1]);
    }
  }
  float bb0 = b1[2 * tid], bb1 = b1[2 * tid + 1];
  uint4 u0, u1;
  u0.x = f2h2(fmaxf(acc[0][0] + bb0, 0.f), fmaxf(acc[0][1] + bb1, 0.f));
  u0.y = f2h2(fmaxf(acc[1][0] + bb0, 0.f), fmaxf(acc[1][1] + bb1, 0.f));
  u0.z = f2h2(fmaxf(acc[2][0] + bb0, 0.f), fmaxf(acc[2][1] + bb1, 0.f));
  u0.w = f2h2(fmaxf(acc[3][0] + bb0, 0.f), fmaxf(acc[3][1] + bb1, 0.f));
  u1.x = f2h2(fmaxf(acc[4][0] + bb0, 0.f), fmaxf(acc[4][1] + bb1, 0.f));
  u1.y = f2h2(fmaxf(acc[5][0] + bb0, 0.f), fmaxf(acc[5][1] + bb1, 0.f));
  u1.z = f2h2(fmaxf(acc[6][0] + bb0, 0.f), fmaxf(acc[6][1] + bb1, 0.f));
  u1.w = f2h2(fmaxf(acc[7][0] + bb0, 0.f), fmaxf(acc[7][1] + bb1, 0.f));
  *(uint4*)&y1p[(size_t)tid * NG + g0] = u0;
  *(uint4*)&y1p[(size_t)tid * NG + g0 + 4] = u1;
}

// R24: dense2 via v_dot2_f32_f16. R23 post-mortem: fp16-x + cvt was VALU-
// instruction-bound (40 ops/k/thread). dot2 contracts k-PAIRS: per k2
// (=2 k) per thread: 2 ds_read_b128 (x: 8 half2) + 1 ds_read_b128 (w: 4
// half2) + 32 dot2 (64 MACs). VALU floor ~14 us, LDS floor ~31 us.
// fp32 accumulate; W2 fp16 rounding is the only new error source.
#define DK2 16  // k2 per phase = 32 k
__global__ void __launch_bounds__(256) k_dense2(const unsigned int* __restrict__ y1p,
                                                const unsigned int* __restrict__ W2h,
                                                const float* __restrict__ b2,
                                                const float* __restrict__ ow,
                                                float* __restrict__ out) {
  __shared__ unsigned int xs[DK2 * 128];  // [k2][g] half2, 8 KB
  __shared__ unsigned int ws[DK2 * 64];   // [k2][j] half2, 4 KB
  __shared__ float po[128];
  int tid = threadIdx.x;  // 256
  int g0 = (blockIdx.x & 63) * 128;
  int j0 = (blockIdx.x >> 6) * 64;
  int ga8 = (tid & 15) * 8;  // 8 contiguous g
  int jb = (tid >> 4) * 4;   // j quad

  float acc[4][8];  // [j][g]
#pragma unroll
  for (int jl = 0; jl < 4; jl++) {
    float bb = b2[j0 + jb + jl];
#pragma unroll
    for (int gg = 0; gg < 8; gg++) acc[jl][gg] = bb;
  }

  for (int kb2 = 0; kb2 < 256; kb2 += DK2) {
    __syncthreads();
    // stage x-tile [16 k2][128 g] half2: 512 uint4, 2/thread
#pragma unroll
    for (int i = 0; i < 2; i++) {
      int f = tid + 256 * i;
      int kr = f >> 5, gc = f & 31;  // 32 uint4 per 128-half2 row
      ((uint4*)xs)[f] = *(const uint4*)&y1p[(size_t)(kb2 + kr) * NG + g0 + gc * 4];
    }
    // stage W-tile [16 k2][64 j] half2: 256 uint4, 1/thread
    {
      int kr = tid >> 4, jc = tid & 15;
      ((uint4*)ws)[tid] = *(const uint4*)&W2h[(size_t)(kb2 + kr) * 512 + j0 + jc * 4];
    }
    __syncthreads();
#pragma unroll 4
    for (int k2 = 0; k2 < DK2; k2++) {
      uint4 xa = *(const uint4*)&xs[k2 * 128 + ga8];      // g 0..3
      uint4 xb = *(const uint4*)&xs[k2 * 128 + ga8 + 4];  // g 4..7
      uint4 wq = *(const uint4*)&ws[k2 * 64 + jb];        // j 0..3
      unsigned int xv[8] = {xa.x, xa.y, xa.z, xa.w, xb.x, xb.y, xb.z, xb.w};
      unsigned int wv[4] = {wq.x, wq.y, wq.z, wq.w};
#pragma unroll
      for (int jj = 0; jj < 4; jj++)
#pragma unroll
        for (int gg = 0; gg < 8; gg++)
          acc[jj][gg] = fdot2(wv[jj], xv[gg], acc[jj][gg]);
    }
  }

  // fused out-epilogue (R18/R23 scheme)
  if (tid < 128) po[tid] = 0.f;
  __syncthreads();
  float4 owv = *(const float4*)&ow[j0 + jb];
#pragma unroll
  for (int gg = 0; gg < 8; gg++) {
    float pv = fmaxf(acc[0][gg], 0.f) * owv.x + fmaxf(acc[1][gg], 0.f) * owv.y +
               fmaxf(acc[2][gg], 0.f) * owv.z + fmaxf(acc[3][gg], 0.f) * owv.w;
    // lanes l, l^16, l^32, l^48 share tid&15 -> same ga8
    pv += __shfl_xor(pv, 16);
    pv += __shfl_xor(pv, 32);
    if ((tid & 48) == 0) atomicAdd(&po[ga8 + gg], pv);
  }
  __syncthreads();
  if (tid < 128) atomicAdd(&out[g0 + tid], po[tid]);
}

extern "C" void kernel_launch(void* const* d_in, const int* in_sizes, int n_in,
                              void* d_out, int out_size, void* d_ws, size_t ws_size,
                              hipStream_t stream) {
  const float* x_mol    = (const float*)d_in[0];
  const float* x_adduct = (const float*)d_in[1];
  const int*   edge_src = (const int*)d_in[2];
  const int*   edge_dst = (const int*)d_in[3];
  const int*   graph_ids= (const int*)d_in[4];
  const float* gcn_W    = (const float*)d_in[5];
  const float* gcn_b    = (const float*)d_in[6];
  const float* d1W      = (const float*)d_in[7];
  const float* d1b      = (const float*)d_in[8];
  const float* d2W      = (const float*)d_in[9];
  const float* d2b      = (const float*)d_in[10];
  const float* oW       = (const float*)d_in[11];
  const float* obias    = (const float*)d_in[12];
  float* out = (float*)d_out;

  char* p = (char*)d_ws;
  auto alloc = [&](size_t bytes) {
    char* q = p;
    p += (bytes + 255) & ~(size_t)255;
    return q;
  };
  int*          counts = (int*)alloc((size_t)NN * 4);
  int*          rp     = (int*)alloc((size_t)(NN + 1) * 4);
  int*          bsum   = (int*)alloc(1024 * 4);
  float*        rsq    = (float*)alloc((size_t)NN * 4);
  int*          rank   = (int*)alloc((size_t)NE * 4);
  int*          csr_s  = (int*)alloc((size_t)NE * 4);
  uint2*        th_a   = (uint2*)alloc((size_t)NN * 64 * 2);  // fp16 t rows
  uint2*        th_b   = (uint2*)alloc((size_t)NN * 64 * 2);
  float*        r      = (float*)alloc((size_t)NG * 64 * 4);
  unsigned int* y1p    = (unsigned int*)alloc((size_t)256 * NG * 4);  // paired y1
  unsigned int* W2h    = (unsigned int*)alloc((size_t)256 * 512 * 4); // paired W2

  hipMemsetAsync(counts, 0, (size_t)NN * 4, stream);
  hipMemsetAsync(r, 0, (size_t)NG * 64 * 4, stream);
  k_packW<<<512, 256, 0, stream>>>(d2W, W2h);
  k_count<<<NE / 256, 256, 0, stream>>>(edge_dst, counts, rank);
  k_scan1<<<NN / 256, 256, 0, stream>>>(counts, rp, bsum);
  k_scan2<<<1, 1024, 0, stream>>>(bsum);
  k_scan3<<<NN / 256, 256, 0, stream>>>(counts, rp, bsum, rsq);
  k_fill<<<8 * (NE / FILL_CHUNK), 256, 0, stream>>>(edge_src, edge_dst, rank, rp, csr_s);

  // t1 = transform(x_mol); t2 = aggT(t1); t3 = aggT(t2); r = aggR(t3)
  k_transform<<<NN / 64, 256, 0, stream>>>(x_mol, gcn_W, gcn_b, rsq, th_a);
  k_aggT<<<NN / 64, 256, 0, stream>>>(th_a, rp, csr_s, rsq,
                                      gcn_W + (size_t)1 * 64 * 64,
                                      gcn_b + (size_t)1 * 64, th_b);
  k_aggT<<<NN / 64, 256, 0, stream>>>(th_b, rp, csr_s, rsq,
                                      gcn_W + (size_t)2 * 64 * 64,
                                      gcn_b + (size_t)2 * 64, th_a);
  k_aggR<<<NN / 64, 256, 0, stream>>>(th_a, rp, csr_s, rsq, graph_ids, r);

  k_dense1<<<NG / 8, 256, 0, stream>>>(r, x_adduct, d1W, d1b, obias, out, y1p);
  k_dense2<<<512, 256, 0, stream>>>(y1p, W2h, d2b, oW, out);
}

// Round 13
// 422.477 us; speedup vs baseline: 1.1245x; 1.0553x over previous
//
#include <hip/hip_runtime.h>
#include <hip/hip_fp16.h>

#define NN 262144   // nodes
#define NE 1048576  // edges
#define NG 8192     // graphs
#define FD 64       // feature dim
#define AD 8        // adduct dim
#define DN 512      // dense dim

// ---------------- CSR build ----------------
__global__ void k_count(const int* __restrict__ dst, int* __restrict__ counts,
                        int* __restrict__ rank) {
  int e = blockIdx.x * 256 + threadIdx.x;
  rank[e] = atomicAdd(&counts[dst[e]], 1);
}

__global__ void k_scan1(const int* __restrict__ counts, int* __restrict__ rp,
                        int* __restrict__ bsum) {
  __shared__ int s[256];
  int tid = threadIdx.x;
  int i = blockIdx.x * 256 + tid;
  int orig = counts[i];
  s[tid] = orig;
  __syncthreads();
  for (int off = 1; off < 256; off <<= 1) {
    int v = (tid >= off) ? s[tid - off] : 0;
    __syncthreads();
    s[tid] += v;
    __syncthreads();
  }
  rp[i] = s[tid] - orig;  // block-local exclusive scan
  if (tid == 255) bsum[blockIdx.x] = s[tid];
}

__global__ void k_scan2(int* __restrict__ bsum) {
  __shared__ int s[1024];
  int tid = threadIdx.x;
  int orig = bsum[tid];
  s[tid] = orig;
  __syncthreads();
  for (int off = 1; off < 1024; off <<= 1) {
    int v = (tid >= off) ? s[tid - off] : 0;
    __syncthreads();
    s[tid] += v;
    __syncthreads();
  }
  bsum[tid] = s[tid] - orig;  // exclusive
}

__global__ void k_scan3(const int* __restrict__ counts, int* __restrict__ rp,
                        const int* __restrict__ bsum, float* __restrict__ rsq) {
  int i = blockIdx.x * 256 + threadIdx.x;
  rp[i] = rp[i] + bsum[blockIdx.x];
  rsq[i] = rsqrtf((float)(counts[i] + 1));
  if (i == 0) rp[NN] = NE;
}

// Atomic-free XCD-partitioned scatter (validated R14). Plain src payload.
#define FILL_EPT 16
#define FILL_CHUNK (256 * FILL_EPT)
__global__ void k_fill(const int* __restrict__ src, const int* __restrict__ dst,
                       const int* __restrict__ rank, const int* __restrict__ rp,
                       int* __restrict__ csr_s) {
  int xcd = blockIdx.x & 7;
  int chunk = blockIdx.x >> 3;
  int base = chunk * FILL_CHUNK + threadIdx.x;
#pragma unroll
  for (int i = 0; i < FILL_EPT; i++) {
    int e = base + i * 256;
    int d = dst[e];
    if ((d >> 15) == xcd) {
      csr_s[rp[d] + rank[e]] = src[e];
    }
  }
}

// ---------------- fp16 helpers (R19/R23/R24, validated) ----------------
__device__ __forceinline__ float4 ldrow_h(const uint2* __restrict__ th2,
                                          size_t n, int ln) {
  uint2 u = th2[n * 16 + ln];
  __half2 p0 = *reinterpret_cast<__half2*>(&u.x);
  __half2 p1 = *reinterpret_cast<__half2*>(&u.y);
  float2 f0 = __half22float2(p0);
  float2 f1 = __half22float2(p1);
  return make_float4(f0.x, f0.y, f1.x, f1.y);
}

__device__ __forceinline__ void strow_h(uint2* __restrict__ th2, size_t idx,
                                        float x, float y, float z, float w) {
  __half2 p0 = __floats2half2_rn(x, y);
  __half2 p1 = __floats2half2_rn(z, w);
  uint2 u;
  u.x = *reinterpret_cast<unsigned int*>(&p0);
  u.y = *reinterpret_cast<unsigned int*>(&p1);
  th2[idx] = u;
}

__device__ __forceinline__ unsigned int f2h2(float x, float y) {
  __half2 p = __floats2half2_rn(x, y);
  return *reinterpret_cast<unsigned int*>(&p);
}

// R24: fp16-pair dot product with fp32 accumulate (validated: dense2 win).
#if __has_builtin(__builtin_amdgcn_fdot2)
typedef _Float16 half2v __attribute__((ext_vector_type(2)));
__device__ __forceinline__ float fdot2(unsigned int a, unsigned int b, float c) {
  half2v ah = __builtin_bit_cast(half2v, a);
  half2v bh = __builtin_bit_cast(half2v, b);
  return __builtin_amdgcn_fdot2(ah, bh, c, false);
}
#else
__device__ __forceinline__ float fdot2(unsigned int a, unsigned int b, float c) {
  float2 af = __half22float2(*reinterpret_cast<__half2*>(&a));
  float2 bf = __half22float2(*reinterpret_cast<__half2*>(&b));
  return fmaf(af.y, bf.y, fmaf(af.x, bf.x, c));
}
#endif

// ---------------- GCN layer 1: t' = (x @ W + b) * rsq[n]  (fp16 out) ------
#define HS 68  // row stride (floats): 272 B, 16B-aligned, breaks pow2 banks
__global__ void __launch_bounds__(256) k_transform(const float* __restrict__ hin,
                                                   const float* __restrict__ W,
                                                   const float* __restrict__ b,
                                                   const float* __restrict__ rsq,
                                                   uint2* __restrict__ tout) {
  __shared__ float hsT[64 * HS];  // [k][n]  17.4 KB
  int tid = threadIdx.x;
  size_t base = (size_t)blockIdx.x * 64 * 64;

  const float4* h4 = (const float4*)(hin + base);
#pragma unroll
  for (int j = 0; j < 4; j++) {
    int f = tid + 256 * j;
    int n = f >> 4, kq = f & 15;
    float4 v = h4[f];
    hsT[(4 * kq + 0) * HS + n] = v.x;
    hsT[(4 * kq + 1) * HS + n] = v.y;
    hsT[(4 * kq + 2) * HS + n] = v.z;
    hsT[(4 * kq + 3) * HS + n] = v.w;
  }
  __syncthreads();

  int n0 = (tid >> 4) * 4;
  int c0 = (tid & 15) * 4;
  float acc[4][4];
#pragma unroll
  for (int i = 0; i < 4; i++)
#pragma unroll
    for (int j = 0; j < 4; j++) acc[i][j] = b[c0 + j];

#pragma unroll 4
  for (int k = 0; k < 64; k++) {
    float4 av = *(const float4*)&hsT[k * HS + n0];   // ds_read_b128
    float4 bv = *(const float4*)&W[k * 64 + c0];     // global, L1-hit broadcast
    acc[0][0] = fmaf(av.x, bv.x, acc[0][0]);
    acc[0][1] = fmaf(av.x, bv.y, acc[0][1]);
    acc[0][2] = fmaf(av.x, bv.z, acc[0][2]);
    acc[0][3] = fmaf(av.x, bv.w, acc[0][3]);
    acc[1][0] = fmaf(av.y, bv.x, acc[1][0]);
    acc[1][1] = fmaf(av.y, bv.y, acc[1][1]);
    acc[1][2] = fmaf(av.y, bv.z, acc[1][2]);
    acc[1][3] = fmaf(av.y, bv.w, acc[1][3]);
    acc[2][0] = fmaf(av.z, bv.x, acc[2][0]);
    acc[2][1] = fmaf(av.z, bv.y, acc[2][1]);
    acc[2][2] = fmaf(av.z, bv.z, acc[2][2]);
    acc[2][3] = fmaf(av.z, bv.w, acc[2][3]);
    acc[3][0] = fmaf(av.w, bv.x, acc[3][0]);
    acc[3][1] = fmaf(av.w, bv.y, acc[3][1]);
    acc[3][2] = fmaf(av.w, bv.z, acc[3][2]);
    acc[3][3] = fmaf(av.w, bv.w, acc[3][3]);
  }

  int nbase = blockIdx.x * 64;
#pragma unroll
  for (int i = 0; i < 4; i++) {
    float rs = rsq[nbase + n0 + i];
    strow_h(tout, (size_t)(nbase + n0 + i) * 16 + (c0 >> 2),
            acc[i][0] * rs, acc[i][1] * rs, acc[i][2] * rs, acc[i][3] * rs);
  }
}

// ---------------- aggregation core (R16 engine, fp16 gather) ----------------
// fp32-hacc variant (used by k_aggR).
__device__ __forceinline__ void aggregate_nodes(const uint2* __restrict__ th2,
                                                const int* __restrict__ rp,
                                                const int* __restrict__ csr_s,
                                                const float* __restrict__ rsq,
                                                float* __restrict__ hacc,
                                                int nbase, int grp, int ln) {
  for (int r = 0; r < 4; r++) {
    int n = nbase + r * 16 + grp;
    int beg = rp[n], end = rp[n + 1];
    float rn = rsq[n];
    float4 a0 = ldrow_h(th2, (size_t)n, ln);  // self term t'[n]
    float4 a1 = make_float4(0.f, 0.f, 0.f, 0.f);
    float4 a2 = make_float4(0.f, 0.f, 0.f, 0.f);
    float4 a3 = make_float4(0.f, 0.f, 0.f, 0.f);

    int idx = beg;
    for (; idx + 4 <= end; idx += 4) {
      int s0 = csr_s[idx + 0];
      int s1 = csr_s[idx + 1];
      int s2 = csr_s[idx + 2];
      int s3 = csr_s[idx + 3];
      float4 v0 = ldrow_h(th2, (size_t)s0, ln);
      float4 v1 = ldrow_h(th2, (size_t)s1, ln);
      float4 v2 = ldrow_h(th2, (size_t)s2, ln);
      float4 v3 = ldrow_h(th2, (size_t)s3, ln);
      a0.x += v0.x; a0.y += v0.y; a0.z += v0.z; a0.w += v0.w;
      a1.x += v1.x; a1.y += v1.y; a1.z += v1.z; a1.w += v1.w;
      a2.x += v2.x; a2.y += v2.y; a2.z += v2.z; a2.w += v2.w;
      a3.x += v3.x; a3.y += v3.y; a3.z += v3.z; a3.w += v3.w;
    }
    if (idx + 2 <= end) {
      int s0 = csr_s[idx + 0];
      int s1 = csr_s[idx + 1];
      float4 v0 = ldrow_h(th2, (size_t)s0, ln);
      float4 v1 = ldrow_h(th2, (size_t)s1, ln);
      a0.x += v0.x; a0.y += v0.y; a0.z += v0.z; a0.w += v0.w;
      a1.x += v1.x; a1.y += v1.y; a1.z += v1.z; a1.w += v1.w;
      idx += 2;
    }
    if (idx < end) {
      int s0 = csr_s[idx];
      float4 v0 = ldrow_h(th2, (size_t)s0, ln);
      a0.x += v0.x; a0.y += v0.y; a0.z += v0.z; a0.w += v0.w;
    }
    int nl = r * 16 + grp;
    float4 v;
    v.x = fmaxf(rn * ((a0.x + a1.x) + (a2.x + a3.x)), 0.f);
    v.y = fmaxf(rn * ((a0.y + a1.y) + (a2.y + a3.y)), 0.f);
    v.z = fmaxf(rn * ((a0.z + a1.z) + (a2.z + a3.z)), 0.f);
    v.w = fmaxf(rn * ((a0.w + a1.w) + (a2.w + a3.w)), 0.f);
    *(float4*)&hacc[nl * HS + 4 * ln] = v;  // 2-way wrap -> conflict-free
  }
}

// ---------------- R25: pack GCN W layers 1,2 into k-paired half2 ----------
__global__ void k_packWg(const float* __restrict__ W, unsigned int* __restrict__ Wp) {
  int idx = blockIdx.x * 256 + threadIdx.x;  // 2 layers x 32 k2 x 64 c
  int L = idx >> 11;
  int k2 = (idx >> 6) & 31;
  int c = idx & 63;
  const float* Wl = W + (size_t)(L + 1) * 64 * 64;
  Wp[idx] = f2h2(Wl[(size_t)(2 * k2) * 64 + c], Wl[(size_t)(2 * k2 + 1) * 64 + c]);
}

// R25: fused aggregate + dot2 transform. R24 post-mortem: aggT's fp32 GEMM
// (64 k-iters x (4 LDS broadcast + 1 global W + 16 fma)) was ~40% of its
// 69.7 us. Now: h' tile stored PACKED half2 (it was rounding to fp16 on
// output anyway), W pre-packed fp16, staged to LDS at kernel start (copy
// overlaps gather latency, R15-validated). GEMM per k2: 4 b32 broadcast +
// 1 b128 + 16 dot2 -- half the iterations, half the VALU, zero global W.
#define HS2 34  // hacc2 row stride (u32): 136 B, breaks pow2 banks
__global__ void __launch_bounds__(256) k_aggT(const uint2* __restrict__ tin,
                                              const int* __restrict__ rp,
                                              const int* __restrict__ csr_s,
                                              const float* __restrict__ rsq,
                                              const unsigned int* __restrict__ Wp,
                                              const float* __restrict__ b,
                                              uint2* __restrict__ tout) {
  __shared__ unsigned int hacc2[64 * HS2];  // [n][k2] packed half2, 8.7 KB
  __shared__ unsigned int ws[32 * 64];      // [k2][c] packed half2, 8 KB
  int tid = threadIdx.x;
  int grp = tid >> 4;
  int ln = tid & 15;
  int nbase = blockIdx.x * 64;

  // stage packed W (2048 u32): issued first, completes under gather latency
#pragma unroll
  for (int i = 0; i < 2; i++)
    ((uint4*)ws)[tid + 256 * i] = ((const uint4*)Wp)[tid + 256 * i];

  // gather (R16 engine), result packed to half2 pairs
  for (int r = 0; r < 4; r++) {
    int n = nbase + r * 16 + grp;
    int beg = rp[n], end = rp[n + 1];
    float rn = rsq[n];
    float4 a0 = ldrow_h(tin, (size_t)n, ln);  // self term
    float4 a1 = make_float4(0.f, 0.f, 0.f, 0.f);
    float4 a2 = make_float4(0.f, 0.f, 0.f, 0.f);
    float4 a3 = make_float4(0.f, 0.f, 0.f, 0.f);

    int idx = beg;
    for (; idx + 4 <= end; idx += 4) {
      int s0 = csr_s[idx + 0];
      int s1 = csr_s[idx + 1];
      int s2 = csr_s[idx + 2];
      int s3 = csr_s[idx + 3];
      float4 v0 = ldrow_h(tin, (size_t)s0, ln);
      float4 v1 = ldrow_h(tin, (size_t)s1, ln);
      float4 v2 = ldrow_h(tin, (size_t)s2, ln);
      float4 v3 = ldrow_h(tin, (size_t)s3, ln);
      a0.x += v0.x; a0.y += v0.y; a0.z += v0.z; a0.w += v0.w;
      a1.x += v1.x; a1.y += v1.y; a1.z += v1.z; a1.w += v1.w;
      a2.x += v2.x; a2.y += v2.y; a2.z += v2.z; a2.w += v2.w;
      a3.x += v3.x; a3.y += v3.y; a3.z += v3.z; a3.w += v3.w;
    }
    if (idx + 2 <= end) {
      int s0 = csr_s[idx + 0];
      int s1 = csr_s[idx + 1];
      float4 v0 = ldrow_h(tin, (size_t)s0, ln);
      float4 v1 = ldrow_h(tin, (size_t)s1, ln);
      a0.x += v0.x; a0.y += v0.y; a0.z += v0.z; a0.w += v0.w;
      a1.x += v1.x; a1.y += v1.y; a1.z += v1.z; a1.w += v1.w;
      idx += 2;
    }
    if (idx < end) {
      int s0 = csr_s[idx];
      float4 v0 = ldrow_h(tin, (size_t)s0, ln);
      a0.x += v0.x; a0.y += v0.y; a0.z += v0.z; a0.w += v0.w;
    }
    int nl = r * 16 + grp;
    float vx = fmaxf(rn * ((a0.x + a1.x) + (a2.x + a3.x)), 0.f);
    float vy = fmaxf(rn * ((a0.y + a1.y) + (a2.y + a3.y)), 0.f);
    float vz = fmaxf(rn * ((a0.z + a1.z) + (a2.z + a3.z)), 0.f);
    float vw = fmaxf(rn * ((a0.w + a1.w) + (a2.w + a3.w)), 0.f);
    // lane ln owns features 4ln..4ln+3 -> k2 pairs 2ln, 2ln+1 (ds_write_b64)
    *(uint2*)&hacc2[nl * HS2 + 2 * ln] = make_uint2(f2h2(vx, vy), f2h2(vz, vw));
  }
  __syncthreads();

  // dot2 GEMM: tout[n][c] = (h'[n][:] @ W + b) * rsq[n]
  int n0 = (tid >> 4) * 4;
  int c0 = (tid & 15) * 4;
  float acc[4][4];
#pragma unroll
  for (int i = 0; i < 4; i++)
#pragma unroll
    for (int j = 0; j < 4; j++) acc[i][j] = b[c0 + j];

#pragma unroll 4
  for (int k2 = 0; k2 < 32; k2++) {
    unsigned int a0 = hacc2[(n0 + 0) * HS2 + k2];  // same-addr broadcast
    unsigned int a1 = hacc2[(n0 + 1) * HS2 + k2];
    unsigned int a2 = hacc2[(n0 + 2) * HS2 + k2];
    unsigned int a3 = hacc2[(n0 + 3) * HS2 + k2];
    uint4 wq = *(const uint4*)&ws[k2 * 64 + c0];   // ds_read_b128
    acc[0][0] = fdot2(a0, wq.x, acc[0][0]);
    acc[0][1] = fdot2(a0, wq.y, acc[0][1]);
    acc[0][2] = fdot2(a0, wq.z, acc[0][2]);
    acc[0][3] = fdot2(a0, wq.w, acc[0][3]);
    acc[1][0] = fdot2(a1, wq.x, acc[1][0]);
    acc[1][1] = fdot2(a1, wq.y, acc[1][1]);
    acc[1][2] = fdot2(a1, wq.z, acc[1][2]);
    acc[1][3] = fdot2(a1, wq.w, acc[1][3]);
    acc[2][0] = fdot2(a2, wq.x, acc[2][0]);
    acc[2][1] = fdot2(a2, wq.y, acc[2][1]);
    acc[2][2] = fdot2(a2, wq.z, acc[2][2]);
    acc[2][3] = fdot2(a2, wq.w, acc[2][3]);
    acc[3][0] = fdot2(a3, wq.x, acc[3][0]);
    acc[3][1] = fdot2(a3, wq.y, acc[3][1]);
    acc[3][2] = fdot2(a3, wq.z, acc[3][2]);
    acc[3][3] = fdot2(a3, wq.w, acc[3][3]);
  }

#pragma unroll
  for (int i = 0; i < 4; i++) {
    float rs = rsq[nbase + n0 + i];
    strow_h(tout, (size_t)(nbase + n0 + i) * 16 + (c0 >> 2),
            acc[i][0] * rs, acc[i][1] * rs, acc[i][2] * rs, acc[i][3] * rs);
  }
}

// ---------------- R18: fused final aggregate + readout (fp32 path) -------
__global__ void __launch_bounds__(256) k_aggR(const uint2* __restrict__ tin,
                                              const int* __restrict__ rp,
                                              const int* __restrict__ csr_s,
                                              const float* __restrict__ rsq,
                                              const int* __restrict__ gids,
                                              float* __restrict__ r) {
  __shared__ float hacc[64 * HS];
  __shared__ int gl[64];
  int tid = threadIdx.x;
  int grp = tid >> 4;
  int ln = tid & 15;
  int nbase = blockIdx.x * 64;
  if (tid < 64) gl[tid] = gids[nbase + tid];

  aggregate_nodes(tin, rp, csr_s, rsq, hacc, nbase, grp, ln);
  __syncthreads();

  // Segmented reduce: wave w handles rows [w*16, w*16+16), lane = column.
  int c = tid & 63;
  int row0 = (tid >> 6) * 16;
  int cur = gl[row0];
  float run = 0.f;
  for (int rr = 0; rr < 16; rr++) {
    int g = gl[row0 + rr];
    float v = hacc[(row0 + rr) * HS + c];
    if (g != cur) {
      atomicAdd(&r[(size_t)cur * 64 + c], run);
      cur = g;
      run = v;
    } else {
      run += v;
    }
  }
  atomicAdd(&r[(size_t)cur * 64 + c], run);
}

// ---------------- R24: pack W2 into k-paired half2 ----------------
__global__ void k_packW(const float* __restrict__ W2, unsigned int* __restrict__ W2h) {
  int idx = blockIdx.x * 256 + threadIdx.x;  // 256 k2 x 512 j
  int k2 = idx >> 9, j = idx & 511;
  W2h[idx] = f2h2(W2[(size_t)(2 * k2) * 512 + j], W2[(size_t)(2 * k2 + 1) * 512 + j]);
}

// ---------------- Dense head ----------------
// R24: dense1 emits y1 as k-paired half2 for dense2's dot2.
__global__ void __launch_bounds__(256) k_dense1(const float* __restrict__ r,
                                                const float* __restrict__ xa,
                                                const float* __restrict__ W1,
                                                const float* __restrict__ b1,
                                                const float* __restrict__ ob,
                                                float* __restrict__ out,
                                                unsigned int* __restrict__ y1p) {
  __shared__ float xs[8 * 72];
  int tid = threadIdx.x;
  int g0 = blockIdx.x * 8;
  if (tid < 8) out[g0 + tid] = ob[0];
  for (int i = tid; i < 8 * 72; i += 256) {
    int g = i / 72, k = i % 72;
    xs[i] = (k < 64) ? r[(size_t)(g0 + g) * 64 + k] : xa[(size_t)(g0 + g) * 8 + (k - 64)];
  }
  __syncthreads();
  float acc[8][2];
#pragma unroll
  for (int g = 0; g < 8; g++) { acc[g][0] = 0.f; acc[g][1] = 0.f; }
  for (int k = 0; k < 72; k++) {
    float2 wp = *(const float2*)&W1[k * 512 + 2 * tid];  // adjacent j-pair
#pragma unroll
    for (int g = 0; g < 8; g++) {
      float xv = xs[g * 72 + k];
      acc[g][0] = fmaf(xv, wp.x, acc[g][0]);
      acc[g][1] = fmaf(xv, wp.y, acc[g][1]);
    }
  }
  float bb0 = b1[2 * tid], bb1 = b1[2 * tid + 1];
  uint4 u0, u1;
  u0.x = f2h2(fmaxf(acc[0][0] + bb0, 0.f), fmaxf(acc[0][1] + bb1, 0.f));
  u0.y = f2h2(fmaxf(acc[1][0] + bb0, 0.f), fmaxf(acc[1][1] + bb1, 0.f));
  u0.z = f2h2(fmaxf(acc[2][0] + bb0, 0.f), fmaxf(acc[2][1] + bb1, 0.f));
  u0.w = f2h2(fmaxf(acc[3][0] + bb0, 0.f), fmaxf(acc[3][1] + bb1, 0.f));
  u1.x = f2h2(fmaxf(acc[4][0] + bb0, 0.f), fmaxf(acc[4][1] + bb1, 0.f));
  u1.y = f2h2(fmaxf(acc[5][0] + bb0, 0.f), fmaxf(acc[5][1] + bb1, 0.f));
  u1.z = f2h2(fmaxf(acc[6][0] + bb0, 0.f), fmaxf(acc[6][1] + bb1, 0.f));
  u1.w = f2h2(fmaxf(acc[7][0] + bb0, 0.f), fmaxf(acc[7][1] + bb1, 0.f));
  *(uint4*)&y1p[(size_t)tid * NG + g0] = u0;
  *(uint4*)&y1p[(size_t)tid * NG + g0 + 4] = u1;
}

// R24: dense2 via v_dot2_f32_f16 (validated). Per k2 per thread: 3
// ds_read_b128 + 32 dot2 (64 MACs). fp32 accumulate.
#define DK2 16  // k2 per phase = 32 k
__global__ void __launch_bounds__(256) k_dense2(const unsigned int* __restrict__ y1p,
                                                const unsigned int* __restrict__ W2h,
                                                const float* __restrict__ b2,
                                                const float* __restrict__ ow,
                                                float* __restrict__ out) {
  __shared__ unsigned int xs[DK2 * 128];  // [k2][g] half2, 8 KB
  __shared__ unsigned int ws[DK2 * 64];   // [k2][j] half2, 4 KB
  __shared__ float po[128];
  int tid = threadIdx.x;  // 256
  int g0 = (blockIdx.x & 63) * 128;
  int j0 = (blockIdx.x >> 6) * 64;
  int ga8 = (tid & 15) * 8;  // 8 contiguous g
  int jb = (tid >> 4) * 4;   // j quad

  float acc[4][8];  // [j][g]
#pragma unroll
  for (int jl = 0; jl < 4; jl++) {
    float bb = b2[j0 + jb + jl];
#pragma unroll
    for (int gg = 0; gg < 8; gg++) acc[jl][gg] = bb;
  }

  for (int kb2 = 0; kb2 < 256; kb2 += DK2) {
    __syncthreads();
    // stage x-tile [16 k2][128 g] half2: 512 uint4, 2/thread
#pragma unroll
    for (int i = 0; i < 2; i++) {
      int f = tid + 256 * i;
      int kr = f >> 5, gc = f & 31;
      ((uint4*)xs)[f] = *(const uint4*)&y1p[(size_t)(kb2 + kr) * NG + g0 + gc * 4];
    }
    // stage W-tile [16 k2][64 j] half2: 256 uint4, 1/thread
    {
      int kr = tid >> 4, jc = tid & 15;
      ((uint4*)ws)[tid] = *(const uint4*)&W2h[(size_t)(kb2 + kr) * 512 + j0 + jc * 4];
    }
    __syncthreads();
#pragma unroll 4
    for (int k2 = 0; k2 < DK2; k2++) {
      uint4 xa = *(const uint4*)&xs[k2 * 128 + ga8];
      uint4 xb = *(const uint4*)&xs[k2 * 128 + ga8 + 4];
      uint4 wq = *(const uint4*)&ws[k2 * 64 + jb];
      unsigned int xv[8] = {xa.x, xa.y, xa.z, xa.w, xb.x, xb.y, xb.z, xb.w};
      unsigned int wv[4] = {wq.x, wq.y, wq.z, wq.w};
#pragma unroll
      for (int jj = 0; jj < 4; jj++)
#pragma unroll
        for (int gg = 0; gg < 8; gg++)
          acc[jj][gg] = fdot2(wv[jj], xv[gg], acc[jj][gg]);
    }
  }

  // fused out-epilogue (R18/R23 scheme)
  if (tid < 128) po[tid] = 0.f;
  __syncthreads();
  float4 owv = *(const float4*)&ow[j0 + jb];
#pragma unroll
  for (int gg = 0; gg < 8; gg++) {
    float pv = fmaxf(acc[0][gg], 0.f) * owv.x + fmaxf(acc[1][gg], 0.f) * owv.y +
               fmaxf(acc[2][gg], 0.f) * owv.z + fmaxf(acc[3][gg], 0.f) * owv.w;
    pv += __shfl_xor(pv, 16);
    pv += __shfl_xor(pv, 32);
    if ((tid & 48) == 0) atomicAdd(&po[ga8 + gg], pv);
  }
  __syncthreads();
  if (tid < 128) atomicAdd(&out[g0 + tid], po[tid]);
}

extern "C" void kernel_launch(void* const* d_in, const int* in_sizes, int n_in,
                              void* d_out, int out_size, void* d_ws, size_t ws_size,
                              hipStream_t stream) {
  const float* x_mol    = (const float*)d_in[0];
  const float* x_adduct = (const float*)d_in[1];
  const int*   edge_src = (const int*)d_in[2];
  const int*   edge_dst = (const int*)d_in[3];
  const int*   graph_ids= (const int*)d_in[4];
  const float* gcn_W    = (const float*)d_in[5];
  const float* gcn_b    = (const float*)d_in[6];
  const float* d1W      = (const float*)d_in[7];
  const float* d1b      = (const float*)d_in[8];
  const float* d2W      = (const float*)d_in[9];
  const float* d2b      = (const float*)d_in[10];
  const float* oW       = (const float*)d_in[11];
  const float* obias    = (const float*)d_in[12];
  float* out = (float*)d_out;

  char* p = (char*)d_ws;
  auto alloc = [&](size_t bytes) {
    char* q = p;
    p += (bytes + 255) & ~(size_t)255;
    return q;
  };
  int*          counts = (int*)alloc((size_t)NN * 4);
  int*          rp     = (int*)alloc((size_t)(NN + 1) * 4);
  int*          bsum   = (int*)alloc(1024 * 4);
  float*        rsq    = (float*)alloc((size_t)NN * 4);
  int*          rank   = (int*)alloc((size_t)NE * 4);
  int*          csr_s  = (int*)alloc((size_t)NE * 4);
  uint2*        th_a   = (uint2*)alloc((size_t)NN * 64 * 2);  // fp16 t rows
  uint2*        th_b   = (uint2*)alloc((size_t)NN * 64 * 2);
  float*        r      = (float*)alloc((size_t)NG * 64 * 4);
  unsigned int* y1p    = (unsigned int*)alloc((size_t)256 * NG * 4);  // paired y1
  unsigned int* W2h    = (unsigned int*)alloc((size_t)256 * 512 * 4); // paired W2
  unsigned int* Wg     = (unsigned int*)alloc((size_t)2 * 32 * 64 * 4); // paired gcn_W L1,L2

  hipMemsetAsync(counts, 0, (size_t)NN * 4, stream);
  hipMemsetAsync(r, 0, (size_t)NG * 64 * 4, stream);
  k_packW<<<512, 256, 0, stream>>>(d2W, W2h);
  k_packWg<<<16, 256, 0, stream>>>(gcn_W, Wg);
  k_count<<<NE / 256, 256, 0, stream>>>(edge_dst, counts, rank);
  k_scan1<<<NN / 256, 256, 0, stream>>>(counts, rp, bsum);
  k_scan2<<<1, 1024, 0, stream>>>(bsum);
  k_scan3<<<NN / 256, 256, 0, stream>>>(counts, rp, bsum, rsq);
  k_fill<<<8 * (NE / FILL_CHUNK), 256, 0, stream>>>(edge_src, edge_dst, rank, rp, csr_s);

  // t1 = transform(x_mol); t2 = aggT(t1); t3 = aggT(t2); r = aggR(t3)
  k_transform<<<NN / 64, 256, 0, stream>>>(x_mol, gcn_W, gcn_b, rsq, th_a);
  k_aggT<<<NN / 64, 256, 0, stream>>>(th_a, rp, csr_s, rsq, Wg,
                                      gcn_b + (size_t)1 * 64, th_b);
  k_aggT<<<NN / 64, 256, 0, stream>>>(th_b, rp, csr_s, rsq, Wg + 2048,
                                      gcn_b + (size_t)2 * 64, th_a);
  k_aggR<<<NN / 64, 256, 0, stream>>>(th_a, rp, csr_s, rsq, graph_ids, r);

  k_dense1<<<NG / 8, 256, 0, stream>>>(r, x_adduct, d1W, d1b, obias, out, y1p);
  k_dense2<<<512, 256, 0, stream>>>(y1p, W2h, d2b, oW, out);
}

// Round 14
// 398.958 us; speedup vs baseline: 1.1907x; 1.0590x over previous
//
#include <hip/hip_runtime.h>
#include <hip/hip_fp16.h>

#define NN 262144   // nodes
#define NE 1048576  // edges
#define NG 8192     // graphs
#define FD 64       // feature dim
#define AD 8        // adduct dim
#define DN 512      // dense dim

// ---------------- CSR build ----------------
__global__ void k_count(const int* __restrict__ dst, int* __restrict__ counts,
                        int* __restrict__ rank) {
  int e = blockIdx.x * 256 + threadIdx.x;
  rank[e] = atomicAdd(&counts[dst[e]], 1);
}

__global__ void k_scan1(const int* __restrict__ counts, int* __restrict__ rp,
                        int* __restrict__ bsum) {
  __shared__ int s[256];
  int tid = threadIdx.x;
  int i = blockIdx.x * 256 + tid;
  int orig = counts[i];
  s[tid] = orig;
  __syncthreads();
  for (int off = 1; off < 256; off <<= 1) {
    int v = (tid >= off) ? s[tid - off] : 0;
    __syncthreads();
    s[tid] += v;
    __syncthreads();
  }
  rp[i] = s[tid] - orig;  // block-local exclusive scan
  if (tid == 255) bsum[blockIdx.x] = s[tid];
}

__global__ void k_scan2(int* __restrict__ bsum) {
  __shared__ int s[1024];
  int tid = threadIdx.x;
  int orig = bsum[tid];
  s[tid] = orig;
  __syncthreads();
  for (int off = 1; off < 1024; off <<= 1) {
    int v = (tid >= off) ? s[tid - off] : 0;
    __syncthreads();
    s[tid] += v;
    __syncthreads();
  }
  bsum[tid] = s[tid] - orig;  // exclusive
}

__global__ void k_scan3(const int* __restrict__ counts, int* __restrict__ rp,
                        const int* __restrict__ bsum, float* __restrict__ rsq) {
  int i = blockIdx.x * 256 + threadIdx.x;
  rp[i] = rp[i] + bsum[blockIdx.x];
  rsq[i] = rsqrtf((float)(counts[i] + 1));
  if (i == 0) rp[NN] = NE;
}

// Atomic-free XCD-partitioned scatter (validated R14). Plain src payload.
#define FILL_EPT 16
#define FILL_CHUNK (256 * FILL_EPT)
__global__ void k_fill(const int* __restrict__ src, const int* __restrict__ dst,
                       const int* __restrict__ rank, const int* __restrict__ rp,
                       int* __restrict__ csr_s) {
  int xcd = blockIdx.x & 7;
  int chunk = blockIdx.x >> 3;
  int base = chunk * FILL_CHUNK + threadIdx.x;
#pragma unroll
  for (int i = 0; i < FILL_EPT; i++) {
    int e = base + i * 256;
    int d = dst[e];
    if ((d >> 15) == xcd) {
      csr_s[rp[d] + rank[e]] = src[e];
    }
  }
}

// ---------------- fp16 helpers (R19/R23/R24, validated) ----------------
__device__ __forceinline__ float4 ldrow_h(const uint2* __restrict__ th2,
                                          size_t n, int ln) {
  uint2 u = th2[n * 16 + ln];
  __half2 p0 = *reinterpret_cast<__half2*>(&u.x);
  __half2 p1 = *reinterpret_cast<__half2*>(&u.y);
  float2 f0 = __half22float2(p0);
  float2 f1 = __half22float2(p1);
  return make_float4(f0.x, f0.y, f1.x, f1.y);
}

__device__ __forceinline__ void strow_h(uint2* __restrict__ th2, size_t idx,
                                        float x, float y, float z, float w) {
  __half2 p0 = __floats2half2_rn(x, y);
  __half2 p1 = __floats2half2_rn(z, w);
  uint2 u;
  u.x = *reinterpret_cast<unsigned int*>(&p0);
  u.y = *reinterpret_cast<unsigned int*>(&p1);
  th2[idx] = u;
}

__device__ __forceinline__ unsigned int f2h2(float x, float y) {
  __half2 p = __floats2half2_rn(x, y);
  return *reinterpret_cast<unsigned int*>(&p);
}

// R24: fp16-pair dot product with fp32 accumulate (validated).
#if __has_builtin(__builtin_amdgcn_fdot2)
typedef _Float16 half2v __attribute__((ext_vector_type(2)));
__device__ __forceinline__ float fdot2(unsigned int a, unsigned int b, float c) {
  half2v ah = __builtin_bit_cast(half2v, a);
  half2v bh = __builtin_bit_cast(half2v, b);
  return __builtin_amdgcn_fdot2(ah, bh, c, false);
}
#else
__device__ __forceinline__ float fdot2(unsigned int a, unsigned int b, float c) {
  float2 af = __half22float2(*reinterpret_cast<__half2*>(&a));
  float2 bf = __half22float2(*reinterpret_cast<__half2*>(&b));
  return fmaf(af.y, bf.y, fmaf(af.x, bf.x, c));
}
#endif

// ---------------- R25/R26: pack all 3 GCN W layers into k-paired half2 ----
__global__ void k_packWg(const float* __restrict__ W, unsigned int* __restrict__ Wp) {
  int idx = blockIdx.x * 256 + threadIdx.x;  // 3 layers x 32 k2 x 64 c
  int L = idx >> 11;
  int k2 = (idx >> 6) & 31;
  int c = idx & 63;
  const float* Wl = W + (size_t)L * 64 * 64;
  Wp[idx] = f2h2(Wl[(size_t)(2 * k2) * 64 + c], Wl[(size_t)(2 * k2 + 1) * 64 + c]);
}

// ---------------- shared dot2 GEMM over the packed h' tile ----------------
// tout[n][c] = (h2[n][:] @ W + b) * rsq[n]; h2/W packed half2, fp32 acc.
#define HS2 34  // packed row stride (u32): 136 B, breaks pow2 banks
__device__ __forceinline__ void gemm_dot2_store(const unsigned int* __restrict__ h2,
                                                const unsigned int* __restrict__ ws,
                                                const float* __restrict__ b,
                                                const float* __restrict__ rsq,
                                                uint2* __restrict__ tout,
                                                int nbase, int tid) {
  int n0 = (tid >> 4) * 4;
  int c0 = (tid & 15) * 4;
  float acc[4][4];
#pragma unroll
  for (int i = 0; i < 4; i++)
#pragma unroll
    for (int j = 0; j < 4; j++) acc[i][j] = b[c0 + j];

#pragma unroll 4
  for (int k2 = 0; k2 < 32; k2++) {
    unsigned int a0 = h2[(n0 + 0) * HS2 + k2];  // same-addr broadcast
    unsigned int a1 = h2[(n0 + 1) * HS2 + k2];
    unsigned int a2 = h2[(n0 + 2) * HS2 + k2];
    unsigned int a3 = h2[(n0 + 3) * HS2 + k2];
    uint4 wq = *(const uint4*)&ws[k2 * 64 + c0];   // ds_read_b128
    acc[0][0] = fdot2(a0, wq.x, acc[0][0]);
    acc[0][1] = fdot2(a0, wq.y, acc[0][1]);
    acc[0][2] = fdot2(a0, wq.z, acc[0][2]);
    acc[0][3] = fdot2(a0, wq.w, acc[0][3]);
    acc[1][0] = fdot2(a1, wq.x, acc[1][0]);
    acc[1][1] = fdot2(a1, wq.y, acc[1][1]);
    acc[1][2] = fdot2(a1, wq.z, acc[1][2]);
    acc[1][3] = fdot2(a1, wq.w, acc[1][3]);
    acc[2][0] = fdot2(a2, wq.x, acc[2][0]);
    acc[2][1] = fdot2(a2, wq.y, acc[2][1]);
    acc[2][2] = fdot2(a2, wq.z, acc[2][2]);
    acc[2][3] = fdot2(a2, wq.w, acc[2][3]);
    acc[3][0] = fdot2(a3, wq.x, acc[3][0]);
    acc[3][1] = fdot2(a3, wq.y, acc[3][1]);
    acc[3][2] = fdot2(a3, wq.z, acc[3][2]);
    acc[3][3] = fdot2(a3, wq.w, acc[3][3]);
  }

#pragma unroll
  for (int i = 0; i < 4; i++) {
    float rs = rsq[nbase + n0 + i];
    strow_h(tout, (size_t)(nbase + n0 + i) * 16 + (c0 >> 2),
            acc[i][0] * rs, acc[i][1] * rs, acc[i][2] * rs, acc[i][3] * rs);
  }
}

// ---------------- GCN layer 1 (R26: dot2 engine, packed staging) ----------
// R25 post-mortem: k_transform was the last fp32-GEMM kernel (55 us, 3.67M
// bank conflicts from the 4-scalar hsT scatter). Now: x staged as packed
// half2 [n][k2] via ds_write_b64 (bank-minimal: each bank exactly 4
// accesses/wave), W layer-0 pre-packed + LDS-staged under the x loads,
// GEMM = aggT's dot2 loop. One new rounding: x_mol -> fp16.
__global__ void __launch_bounds__(256) k_transform(const float* __restrict__ hin,
                                                   const unsigned int* __restrict__ Wp,
                                                   const float* __restrict__ b,
                                                   const float* __restrict__ rsq,
                                                   uint2* __restrict__ tout) {
  __shared__ unsigned int h2[64 * HS2];  // [n][k2] packed half2, 8.7 KB
  __shared__ unsigned int ws[32 * 64];   // [k2][c] packed half2, 8 KB
  int tid = threadIdx.x;
  size_t base = (size_t)blockIdx.x * 64 * 64;
  int nbase = blockIdx.x * 64;

  // stage packed W first (completes under the x_mol loads)
#pragma unroll
  for (int i = 0; i < 2; i++)
    ((uint4*)ws)[tid + 256 * i] = ((const uint4*)Wp)[tid + 256 * i];

  const float4* h4 = (const float4*)(hin + base);
#pragma unroll
  for (int j = 0; j < 4; j++) {
    int f = tid + 256 * j;
    int n = f >> 4, kq = f & 15;  // node row, k-quad (k = 4kq..4kq+3)
    float4 v = h4[f];
    *(uint2*)&h2[n * HS2 + 2 * kq] = make_uint2(f2h2(v.x, v.y), f2h2(v.z, v.w));
  }
  __syncthreads();

  gemm_dot2_store(h2, ws, b, rsq, tout, nbase, tid);
}

// ---------------- aggregation core (R16 engine, fp16 gather) ----------------
// fp32-hacc variant (used by k_aggR).
#define HS 68
__device__ __forceinline__ void aggregate_nodes(const uint2* __restrict__ th2,
                                                const int* __restrict__ rp,
                                                const int* __restrict__ csr_s,
                                                const float* __restrict__ rsq,
                                                float* __restrict__ hacc,
                                                int nbase, int grp, int ln) {
  for (int r = 0; r < 4; r++) {
    int n = nbase + r * 16 + grp;
    int beg = rp[n], end = rp[n + 1];
    float rn = rsq[n];
    float4 a0 = ldrow_h(th2, (size_t)n, ln);  // self term t'[n]
    float4 a1 = make_float4(0.f, 0.f, 0.f, 0.f);
    float4 a2 = make_float4(0.f, 0.f, 0.f, 0.f);
    float4 a3 = make_float4(0.f, 0.f, 0.f, 0.f);

    int idx = beg;
    for (; idx + 4 <= end; idx += 4) {
      int s0 = csr_s[idx + 0];
      int s1 = csr_s[idx + 1];
      int s2 = csr_s[idx + 2];
      int s3 = csr_s[idx + 3];
      float4 v0 = ldrow_h(th2, (size_t)s0, ln);
      float4 v1 = ldrow_h(th2, (size_t)s1, ln);
      float4 v2 = ldrow_h(th2, (size_t)s2, ln);
      float4 v3 = ldrow_h(th2, (size_t)s3, ln);
      a0.x += v0.x; a0.y += v0.y; a0.z += v0.z; a0.w += v0.w;
      a1.x += v1.x; a1.y += v1.y; a1.z += v1.z; a1.w += v1.w;
      a2.x += v2.x; a2.y += v2.y; a2.z += v2.z; a2.w += v2.w;
      a3.x += v3.x; a3.y += v3.y; a3.z += v3.z; a3.w += v3.w;
    }
    if (idx + 2 <= end) {
      int s0 = csr_s[idx + 0];
      int s1 = csr_s[idx + 1];
      float4 v0 = ldrow_h(th2, (size_t)s0, ln);
      float4 v1 = ldrow_h(th2, (size_t)s1, ln);
      a0.x += v0.x; a0.y += v0.y; a0.z += v0.z; a0.w += v0.w;
      a1.x += v1.x; a1.y += v1.y; a1.z += v1.z; a1.w += v1.w;
      idx += 2;
    }
    if (idx < end) {
      int s0 = csr_s[idx];
      float4 v0 = ldrow_h(th2, (size_t)s0, ln);
      a0.x += v0.x; a0.y += v0.y; a0.z += v0.z; a0.w += v0.w;
    }
    int nl = r * 16 + grp;
    float4 v;
    v.x = fmaxf(rn * ((a0.x + a1.x) + (a2.x + a3.x)), 0.f);
    v.y = fmaxf(rn * ((a0.y + a1.y) + (a2.y + a3.y)), 0.f);
    v.z = fmaxf(rn * ((a0.z + a1.z) + (a2.z + a3.z)), 0.f);
    v.w = fmaxf(rn * ((a0.w + a1.w) + (a2.w + a3.w)), 0.f);
    *(float4*)&hacc[nl * HS + 4 * ln] = v;  // 2-way wrap -> conflict-free
  }
}

// R25: fused aggregate + dot2 transform (validated: 69.7 -> off top-5).
__global__ void __launch_bounds__(256) k_aggT(const uint2* __restrict__ tin,
                                              const int* __restrict__ rp,
                                              const int* __restrict__ csr_s,
                                              const float* __restrict__ rsq,
                                              const unsigned int* __restrict__ Wp,
                                              const float* __restrict__ b,
                                              uint2* __restrict__ tout) {
  __shared__ unsigned int hacc2[64 * HS2];  // [n][k2] packed half2, 8.7 KB
  __shared__ unsigned int ws[32 * 64];      // [k2][c] packed half2, 8 KB
  int tid = threadIdx.x;
  int grp = tid >> 4;
  int ln = tid & 15;
  int nbase = blockIdx.x * 64;

  // stage packed W (completes under gather latency)
#pragma unroll
  for (int i = 0; i < 2; i++)
    ((uint4*)ws)[tid + 256 * i] = ((const uint4*)Wp)[tid + 256 * i];

  // gather (R16 engine), result packed to half2 pairs
  for (int r = 0; r < 4; r++) {
    int n = nbase + r * 16 + grp;
    int beg = rp[n], end = rp[n + 1];
    float rn = rsq[n];
    float4 a0 = ldrow_h(tin, (size_t)n, ln);  // self term
    float4 a1 = make_float4(0.f, 0.f, 0.f, 0.f);
    float4 a2 = make_float4(0.f, 0.f, 0.f, 0.f);
    float4 a3 = make_float4(0.f, 0.f, 0.f, 0.f);

    int idx = beg;
    for (; idx + 4 <= end; idx += 4) {
      int s0 = csr_s[idx + 0];
      int s1 = csr_s[idx + 1];
      int s2 = csr_s[idx + 2];
      int s3 = csr_s[idx + 3];
      float4 v0 = ldrow_h(tin, (size_t)s0, ln);
      float4 v1 = ldrow_h(tin, (size_t)s1, ln);
      float4 v2 = ldrow_h(tin, (size_t)s2, ln);
      float4 v3 = ldrow_h(tin, (size_t)s3, ln);
      a0.x += v0.x; a0.y += v0.y; a0.z += v0.z; a0.w += v0.w;
      a1.x += v1.x; a1.y += v1.y; a1.z += v1.z; a1.w += v1.w;
      a2.x += v2.x; a2.y += v2.y; a2.z += v2.z; a2.w += v2.w;
      a3.x += v3.x; a3.y += v3.y; a3.z += v3.z; a3.w += v3.w;
    }
    if (idx + 2 <= end) {
      int s0 = csr_s[idx + 0];
      int s1 = csr_s[idx + 1];
      float4 v0 = ldrow_h(tin, (size_t)s0, ln);
      float4 v1 = ldrow_h(tin, (size_t)s1, ln);
      a0.x += v0.x; a0.y += v0.y; a0.z += v0.z; a0.w += v0.w;
      a1.x += v1.x; a1.y += v1.y; a1.z += v1.z; a1.w += v1.w;
      idx += 2;
    }
    if (idx < end) {
      int s0 = csr_s[idx];
      float4 v0 = ldrow_h(tin, (size_t)s0, ln);
      a0.x += v0.x; a0.y += v0.y; a0.z += v0.z; a0.w += v0.w;
    }
    int nl = r * 16 + grp;
    float vx = fmaxf(rn * ((a0.x + a1.x) + (a2.x + a3.x)), 0.f);
    float vy = fmaxf(rn * ((a0.y + a1.y) + (a2.y + a3.y)), 0.f);
    float vz = fmaxf(rn * ((a0.z + a1.z) + (a2.z + a3.z)), 0.f);
    float vw = fmaxf(rn * ((a0.w + a1.w) + (a2.w + a3.w)), 0.f);
    *(uint2*)&hacc2[nl * HS2 + 2 * ln] = make_uint2(f2h2(vx, vy), f2h2(vz, vw));
  }
  __syncthreads();

  gemm_dot2_store(hacc2, ws, b, rsq, tout, nbase, tid);
}

// ---------------- R18: fused final aggregate + readout (fp32 path) -------
__global__ void __launch_bounds__(256) k_aggR(const uint2* __restrict__ tin,
                                              const int* __restrict__ rp,
                                              const int* __restrict__ csr_s,
                                              const float* __restrict__ rsq,
                                              const int* __restrict__ gids,
                                              float* __restrict__ r) {
  __shared__ float hacc[64 * HS];
  __shared__ int gl[64];
  int tid = threadIdx.x;
  int grp = tid >> 4;
  int ln = tid & 15;
  int nbase = blockIdx.x * 64;
  if (tid < 64) gl[tid] = gids[nbase + tid];

  aggregate_nodes(tin, rp, csr_s, rsq, hacc, nbase, grp, ln);
  __syncthreads();

  // Segmented reduce: wave w handles rows [w*16, w*16+16), lane = column.
  int c = tid & 63;
  int row0 = (tid >> 6) * 16;
  int cur = gl[row0];
  float run = 0.f;
  for (int rr = 0; rr < 16; rr++) {
    int g = gl[row0 + rr];
    float v = hacc[(row0 + rr) * HS + c];
    if (g != cur) {
      atomicAdd(&r[(size_t)cur * 64 + c], run);
      cur = g;
      run = v;
    } else {
      run += v;
    }
  }
  atomicAdd(&r[(size_t)cur * 64 + c], run);
}

// ---------------- R24: pack W2 into k-paired half2 ----------------
__global__ void k_packW(const float* __restrict__ W2, unsigned int* __restrict__ W2h) {
  int idx = blockIdx.x * 256 + threadIdx.x;  // 256 k2 x 512 j
  int k2 = idx >> 9, j = idx & 511;
  W2h[idx] = f2h2(W2[(size_t)(2 * k2) * 512 + j], W2[(size_t)(2 * k2 + 1) * 512 + j]);
}

// ---------------- Dense head ----------------
// R24: dense1 emits y1 as k-paired half2 for dense2's dot2.
__global__ void __launch_bounds__(256) k_dense1(const float* __restrict__ r,
                                                const float* __restrict__ xa,
                                                const float* __restrict__ W1,
                                                const float* __restrict__ b1,
                                                const float* __restrict__ ob,
                                                float* __restrict__ out,
                                                unsigned int* __restrict__ y1p) {
  __shared__ float xs[8 * 72];
  int tid = threadIdx.x;
  int g0 = blockIdx.x * 8;
  if (tid < 8) out[g0 + tid] = ob[0];
  for (int i = tid; i < 8 * 72; i += 256) {
    int g = i / 72, k = i % 72;
    xs[i] = (k < 64) ? r[(size_t)(g0 + g) * 64 + k] : xa[(size_t)(g0 + g) * 8 + (k - 64)];
  }
  __syncthreads();
  float acc[8][2];
#pragma unroll
  for (int g = 0; g < 8; g++) { acc[g][0] = 0.f; acc[g][1] = 0.f; }
  for (int k = 0; k < 72; k++) {
    float2 wp = *(const float2*)&W1[k * 512 + 2 * tid];  // adjacent j-pair
#pragma unroll
    for (int g = 0; g < 8; g++) {
      float xv = xs[g * 72 + k];
      acc[g][0] = fmaf(xv, wp.x, acc[g][0]);
      acc[g][1] = fmaf(xv, wp.y, acc[g][1]);
    }
  }
  float bb0 = b1[2 * tid], bb1 = b1[2 * tid + 1];
  uint4 u0, u1;
  u0.x = f2h2(fmaxf(acc[0][0] + bb0, 0.f), fmaxf(acc[0][1] + bb1, 0.f));
  u0.y = f2h2(fmaxf(acc[1][0] + bb0, 0.f), fmaxf(acc[1][1] + bb1, 0.f));
  u0.z = f2h2(fmaxf(acc[2][0] + bb0, 0.f), fmaxf(acc[2][1] + bb1, 0.f));
  u0.w = f2h2(fmaxf(acc[3][0] + bb0, 0.f), fmaxf(acc[3][1] + bb1, 0.f));
  u1.x = f2h2(fmaxf(acc[4][0] + bb0, 0.f), fmaxf(acc[4][1] + bb1, 0.f));
  u1.y = f2h2(fmaxf(acc[5][0] + bb0, 0.f), fmaxf(acc[5][1] + bb1, 0.f));
  u1.z = f2h2(fmaxf(acc[6][0] + bb0, 0.f), fmaxf(acc[6][1] + bb1, 0.f));
  u1.w = f2h2(fmaxf(acc[7][0] + bb0, 0.f), fmaxf(acc[7][1] + bb1, 0.f));
  *(uint4*)&y1p[(size_t)tid * NG + g0] = u0;
  *(uint4*)&y1p[(size_t)tid * NG + g0 + 4] = u1;
}

// R24: dense2 via v_dot2_f32_f16 (validated). fp32 accumulate.
#define DK2 16  // k2 per phase = 32 k
__global__ void __launch_bounds__(256) k_dense2(const unsigned int* __restrict__ y1p,
                                                const unsigned int* __restrict__ W2h,
                                                const float* __restrict__ b2,
                                                const float* __restrict__ ow,
                                                float* __restrict__ out) {
  __shared__ unsigned int xs[DK2 * 128];  // [k2][g] half2, 8 KB
  __shared__ unsigned int ws[DK2 * 64];   // [k2][j] half2, 4 KB
  __shared__ float po[128];
  int tid = threadIdx.x;  // 256
  int g0 = (blockIdx.x & 63) * 128;
  int j0 = (blockIdx.x >> 6) * 64;
  int ga8 = (tid & 15) * 8;  // 8 contiguous g
  int jb = (tid >> 4) * 4;   // j quad

  float acc[4][8];  // [j][g]
#pragma unroll
  for (int jl = 0; jl < 4; jl++) {
    float bb = b2[j0 + jb + jl];
#pragma unroll
    for (int gg = 0; gg < 8; gg++) acc[jl][gg] = bb;
  }

  for (int kb2 = 0; kb2 < 256; kb2 += DK2) {
    __syncthreads();
    // stage x-tile [16 k2][128 g] half2: 512 uint4, 2/thread
#pragma unroll
    for (int i = 0; i < 2; i++) {
      int f = tid + 256 * i;
      int kr = f >> 5, gc = f & 31;
      ((uint4*)xs)[f] = *(const uint4*)&y1p[(size_t)(kb2 + kr) * NG + g0 + gc * 4];
    }
    // stage W-tile [16 k2][64 j] half2: 256 uint4, 1/thread
    {
      int kr = tid >> 4, jc = tid & 15;
      ((uint4*)ws)[tid] = *(const uint4*)&W2h[(size_t)(kb2 + kr) * 512 + j0 + jc * 4];
    }
    __syncthreads();
#pragma unroll 4
    for (int k2 = 0; k2 < DK2; k2++) {
      uint4 xa = *(const uint4*)&xs[k2 * 128 + ga8];
      uint4 xb = *(const uint4*)&xs[k2 * 128 + ga8 + 4];
      uint4 wq = *(const uint4*)&ws[k2 * 64 + jb];
      unsigned int xv[8] = {xa.x, xa.y, xa.z, xa.w, xb.x, xb.y, xb.z, xb.w};
      unsigned int wv[4] = {wq.x, wq.y, wq.z, wq.w};
#pragma unroll
      for (int jj = 0; jj < 4; jj++)
#pragma unroll
        for (int gg = 0; gg < 8; gg++)
          acc[jj][gg] = fdot2(wv[jj], xv[gg], acc[jj][gg]);
    }
  }

  // fused out-epilogue (R18/R23 scheme)
  if (tid < 128) po[tid] = 0.f;
  __syncthreads();
  float4 owv = *(const float4*)&ow[j0 + jb];
#pragma unroll
  for (int gg = 0; gg < 8; gg++) {
    float pv = fmaxf(acc[0][gg], 0.f) * owv.x + fmaxf(acc[1][gg], 0.f) * owv.y +
               fmaxf(acc[2][gg], 0.f) * owv.z + fmaxf(acc[3][gg], 0.f) * owv.w;
    pv += __shfl_xor(pv, 16);
    pv += __shfl_xor(pv, 32);
    if ((tid & 48) == 0) atomicAdd(&po[ga8 + gg], pv);
  }
  __syncthreads();
  if (tid < 128) atomicAdd(&out[g0 + tid], po[tid]);
}

extern "C" void kernel_launch(void* const* d_in, const int* in_sizes, int n_in,
                              void* d_out, int out_size, void* d_ws, size_t ws_size,
                              hipStream_t stream) {
  const float* x_mol    = (const float*)d_in[0];
  const float* x_adduct = (const float*)d_in[1];
  const int*   edge_src = (const int*)d_in[2];
  const int*   edge_dst = (const int*)d_in[3];
  const int*   graph_ids= (const int*)d_in[4];
  const float* gcn_W    = (const float*)d_in[5];
  const float* gcn_b    = (const float*)d_in[6];
  const float* d1W      = (const float*)d_in[7];
  const float* d1b      = (const float*)d_in[8];
  const float* d2W      = (const float*)d_in[9];
  const float* d2b      = (const float*)d_in[10];
  const float* oW       = (const float*)d_in[11];
  const float* obias    = (const float*)d_in[12];
  float* out = (float*)d_out;

  char* p = (char*)d_ws;
  auto alloc = [&](size_t bytes) {
    char* q = p;
    p += (bytes + 255) & ~(size_t)255;
    return q;
  };
  int*          counts = (int*)alloc((size_t)NN * 4);
  int*          rp     = (int*)alloc((size_t)(NN + 1) * 4);
  int*          bsum   = (int*)alloc(1024 * 4);
  float*        rsq    = (float*)alloc((size_t)NN * 4);
  int*          rank   = (int*)alloc((size_t)NE * 4);
  int*          csr_s  = (int*)alloc((size_t)NE * 4);
  uint2*        th_a   = (uint2*)alloc((size_t)NN * 64 * 2);  // fp16 t rows
  uint2*        th_b   = (uint2*)alloc((size_t)NN * 64 * 2);
  float*        r      = (float*)alloc((size_t)NG * 64 * 4);
  unsigned int* y1p    = (unsigned int*)alloc((size_t)256 * NG * 4);  // paired y1
  unsigned int* W2h    = (unsigned int*)alloc((size_t)256 * 512 * 4); // paired W2
  unsigned int* Wg     = (unsigned int*)alloc((size_t)3 * 32 * 64 * 4); // paired gcn_W L0-2

  hipMemsetAsync(counts, 0, (size_t)NN * 4, stream);
  hipMemsetAsync(r, 0, (size_t)NG * 64 * 4, stream);
  k_packW<<<512, 256, 0, stream>>>(d2W, W2h);
  k_packWg<<<24, 256, 0, stream>>>(gcn_W, Wg);
  k_count<<<NE / 256, 256, 0, stream>>>(edge_dst, counts, rank);
  k_scan1<<<NN / 256, 256, 0, stream>>>(counts, rp, bsum);
  k_scan2<<<1, 1024, 0, stream>>>(bsum);
  k_scan3<<<NN / 256, 256, 0, stream>>>(counts, rp, bsum, rsq);
  k_fill<<<8 * (NE / FILL_CHUNK), 256, 0, stream>>>(edge_src, edge_dst, rank, rp, csr_s);

  // t1 = transform(x_mol); t2 = aggT(t1); t3 = aggT(t2); r = aggR(t3)
  k_transform<<<NN / 64, 256, 0, stream>>>(x_mol, Wg, gcn_b, rsq, th_a);
  k_aggT<<<NN / 64, 256, 0, stream>>>(th_a, rp, csr_s, rsq, Wg + 2048,
                                      gcn_b + (size_t)1 * 64, th_b);
  k_aggT<<<NN / 64, 256, 0, stream>>>(th_b, rp, csr_s, rsq, Wg + 4096,
                                      gcn_b + (size_t)2 * 64, th_a);
  k_aggR<<<NN / 64, 256, 0, stream>>>(th_a, rp, csr_s, rsq, graph_ids, r);

  k_dense1<<<NG / 8, 256, 0, stream>>>(r, x_adduct, d1W, d1b, obias, out, y1p);
  k_dense2<<<512, 256, 0, stream>>>(y1p, W2h, d2b, oW, out);
}